// Round 1
// baseline (696.305 us; speedup 1.0000x reference)
//
#include <hip/hip_runtime.h>
#include <stdint.h>

#define Bb 4
#define Tt 2048
#define Cc 1024
#define Hh 16
#define HSs 64

typedef __attribute__((ext_vector_type(8))) __bf16 bf16x8;
typedef __attribute__((ext_vector_type(4))) float f32x4;

__device__ __forceinline__ ushort f2bf(float f){
  union { float f; uint u; } c; c.f = f;
  uint r = c.u + 0x7fffu + ((c.u >> 16) & 1u);
  return (ushort)(r >> 16);
}
__device__ __forceinline__ float bf2f(ushort u){
  union { uint u; float f; } c; c.u = ((uint)u) << 16; return c.f;
}
__device__ __forceinline__ __bf16 us2bf(ushort u){
  union { ushort u; __bf16 b; } c; c.u = u; return c.b;
}

// async global->LDS, 16B per lane. LDS dest must be wave-uniform base; HW adds lane*16.
__device__ __forceinline__ void gload16(const void* g, void* l){
  __builtin_amdgcn_global_load_lds(
      (__attribute__((address_space(1))) void*)(g),
      (__attribute__((address_space(3))) void*)(l), 16, 0, 0);
}

// ---------------- elementwise fp32 -> bf16 cast (weights) ----------------
__global__ __launch_bounds__(256) void cast_bf16_kernel(const float* __restrict__ in,
                                                        ushort* __restrict__ out){
  int i = (blockIdx.x * 256 + threadIdx.x) * 4;
  float4 v = *(const float4*)(in + i);
  ushort4 o; o.x = f2bf(v.x); o.y = f2bf(v.y); o.z = f2bf(v.z); o.w = f2bf(v.w);
  *(ushort4*)(out + i) = o;
}

// ---------------- LN1: h1 = LN(x) -> bf16 ----------------
__global__ __launch_bounds__(256) void ln1_kernel(const float* __restrict__ x,
    const float* __restrict__ gw, const float* __restrict__ bw,
    ushort* __restrict__ hout){
  int row = blockIdx.x, tid = threadIdx.x;
  size_t base = (size_t)row * Cc + tid * 4;
  float4 xv = *(const float4*)(x + base);
  float s  = xv.x + xv.y + xv.z + xv.w;
  float ss = xv.x*xv.x + xv.y*xv.y + xv.z*xv.z + xv.w*xv.w;
  #pragma unroll
  for (int off = 1; off < 64; off <<= 1){ s += __shfl_xor(s, off); ss += __shfl_xor(ss, off); }
  __shared__ float red[8];
  int wid = tid >> 6, lane = tid & 63;
  if (lane == 0){ red[wid] = s; red[4 + wid] = ss; }
  __syncthreads();
  s  = red[0] + red[1] + red[2] + red[3];
  ss = red[4] + red[5] + red[6] + red[7];
  float mu = s * (1.0f / Cc);
  float rstd = rsqrtf(ss * (1.0f / Cc) - mu * mu + 1e-5f);
  float4 gv = *(const float4*)(gw + tid * 4);
  float4 bv = *(const float4*)(bw + tid * 4);
  ushort4 o;
  o.x = f2bf((xv.x - mu) * rstd * gv.x + bv.x);
  o.y = f2bf((xv.y - mu) * rstd * gv.y + bv.y);
  o.z = f2bf((xv.z - mu) * rstd * gv.z + bv.z);
  o.w = f2bf((xv.w - mu) * rstd * gv.w + bv.w);
  *(ushort4*)(hout + base) = o;
}

// ---------------- LN2: x2 = x + attn (write to d_out), h2 = LN(x2) -> bf16 ----------------
__global__ __launch_bounds__(256) void ln2_kernel(const float* __restrict__ x,
    const ushort* __restrict__ attnb,
    const float* __restrict__ gw, const float* __restrict__ bw,
    float* __restrict__ x2, ushort* __restrict__ hout){
  int row = blockIdx.x, tid = threadIdx.x;
  size_t base = (size_t)row * Cc + tid * 4;
  float4 xv = *(const float4*)(x + base);
  ushort4 av = *(const ushort4*)(attnb + base);
  xv.x += bf2f(av.x); xv.y += bf2f(av.y); xv.z += bf2f(av.z); xv.w += bf2f(av.w);
  *(float4*)(x2 + base) = xv;
  float s  = xv.x + xv.y + xv.z + xv.w;
  float ss = xv.x*xv.x + xv.y*xv.y + xv.z*xv.z + xv.w*xv.w;
  #pragma unroll
  for (int off = 1; off < 64; off <<= 1){ s += __shfl_xor(s, off); ss += __shfl_xor(ss, off); }
  __shared__ float red[8];
  int wid = tid >> 6, lane = tid & 63;
  if (lane == 0){ red[wid] = s; red[4 + wid] = ss; }
  __syncthreads();
  s  = red[0] + red[1] + red[2] + red[3];
  ss = red[4] + red[5] + red[6] + red[7];
  float mu = s * (1.0f / Cc);
  float rstd = rsqrtf(ss * (1.0f / Cc) - mu * mu + 1e-5f);
  float4 gv = *(const float4*)(gw + tid * 4);
  float4 bv = *(const float4*)(bw + tid * 4);
  ushort4 o;
  o.x = f2bf((xv.x - mu) * rstd * gv.x + bv.x);
  o.y = f2bf((xv.y - mu) * rstd * gv.y + bv.y);
  o.z = f2bf((xv.z - mu) * rstd * gv.z + bv.z);
  o.w = f2bf((xv.w - mu) * rstd * gv.w + bv.w);
  *(ushort4*)(hout + base) = o;
}

// ---------------- GEMM: C[M,N] = A[M,K] (bf16) * W[N,K]^T (bf16), fp32 accum ----------------
// 128x128 tile, BK=64, 4 waves (2x2), 16x16x32 bf16 MFMA, 4x4 frags/wave.
// MODE 0: QKV scatter to [B,H,T,HS] bf16, scaled.  MODE 1: SiLU(acc+bias) -> bf16 row-major.
// MODE 2: acc + bias + of32[idx] -> of32[idx] (residual, final output).
template<int MODE>
__global__ __launch_bounds__(256) void gemm_bt_kernel(
    const ushort* __restrict__ A, const ushort* __restrict__ Bw,
    int N, int K,
    ushort* __restrict__ obf, float* __restrict__ of32,
    const float* __restrict__ bias, float scale)
{
  __shared__ __align__(16) ushort Asm[128 * 64];
  __shared__ __align__(16) ushort Bsm[128 * 64];
  int tid = threadIdx.x;
  int lane = tid & 63, wid = tid >> 6;
  int wm = wid >> 1, wn = wid & 1;
  int m0 = blockIdx.y * 128, n0 = blockIdx.x * 128;
  int srow = lane >> 3, schunk = lane & 7;   // staging: 8 rows x 8 x 16B per wave-instr
  int c = lane & 15, g = lane >> 4;
  f32x4 acc[4][4] = {};

  for (int k0 = 0; k0 < K; k0 += 64){
    #pragma unroll
    for (int it = 0; it < 4; ++it){
      int row = wid * 32 + it * 8 + srow;
      gload16(A  + (size_t)(m0 + row) * K + k0 + schunk * 8,
              Asm + (size_t)(wid * 32 + it * 8) * 64);
      gload16(Bw + (size_t)(n0 + row) * K + k0 + schunk * 8,
              Bsm + (size_t)(wid * 32 + it * 8) * 64);
    }
    __syncthreads();   // drains vmcnt(0): LDS tiles ready
    #pragma unroll
    for (int ks = 0; ks < 2; ++ks){
      bf16x8 af[4], bfr[4];
      #pragma unroll
      for (int mi = 0; mi < 4; ++mi)
        af[mi] = *(const bf16x8*)(Asm + (wm * 64 + mi * 16 + c) * 64 + ks * 32 + g * 8);
      #pragma unroll
      for (int ni = 0; ni < 4; ++ni)
        bfr[ni] = *(const bf16x8*)(Bsm + (wn * 64 + ni * 16 + c) * 64 + ks * 32 + g * 8);
      #pragma unroll
      for (int mi = 0; mi < 4; ++mi)
        #pragma unroll
        for (int ni = 0; ni < 4; ++ni)
          acc[mi][ni] = __builtin_amdgcn_mfma_f32_16x16x32_bf16(af[mi], bfr[ni], acc[mi][ni], 0, 0, 0);
    }
    __syncthreads();   // protect LDS before next stage
  }

  #pragma unroll
  for (int mi = 0; mi < 4; ++mi){
    #pragma unroll
    for (int ni = 0; ni < 4; ++ni){
      #pragma unroll
      for (int r = 0; r < 4; ++r){
        float v = acc[mi][ni][r];
        int m = m0 + wm * 64 + mi * 16 + g * 4 + r;
        int n = n0 + wn * 64 + ni * 16 + c;
        if (MODE == 0){
          v *= scale;
          int b = m >> 11, t = m & (Tt - 1);
          int h = n >> 6,  d = n & 63;
          obf[(((size_t)(b * Hh + h)) * Tt + t) * HSs + d] = f2bf(v);
        } else if (MODE == 1){
          v += bias[n];
          float sv = v / (1.0f + __expf(-v));   // SiLU
          obf[(size_t)m * N + n] = f2bf(sv);
        } else {
          size_t idx = (size_t)m * Cc + n;
          of32[idx] = of32[idx] + v + bias[n];  // x2 + ff
        }
      }
    }
  }
}

// ---------------- causal flash attention ----------------
// grid (T/128, B*H), 256 thr = 4 independent waves, 32 q-rows each, 32-kv chunks.
__global__ __launch_bounds__(256) void attn_kernel(
    const ushort* __restrict__ q, const ushort* __restrict__ k,
    const ushort* __restrict__ v, ushort* __restrict__ attnb)
{
  __shared__ __align__(16) ushort Pl[4][32][32];  // per-wave P tile (bf16)
  int bh = blockIdx.y;
  int wid = threadIdx.x >> 6, lane = threadIdx.x & 63;
  int g = lane >> 4, c = lane & 15;
  int q0 = blockIdx.x * 128 + wid * 32;
  const ushort* Qb = q + (size_t)bh * Tt * HSs;
  const ushort* Kb = k + (size_t)bh * Tt * HSs;
  const ushort* Vb = v + (size_t)bh * Tt * HSs;

  bf16x8 qf[2][2];   // q pre-scaled by 1/8 at projection time
  #pragma unroll
  for (int mi = 0; mi < 2; ++mi)
    #pragma unroll
    for (int ks = 0; ks < 2; ++ks)
      qf[mi][ks] = *(const bf16x8*)(Qb + (size_t)(q0 + mi * 16 + c) * HSs + ks * 32 + g * 8);

  f32x4 o[2][4] = {};
  float mrow[2][4], lrow[2][4];
  #pragma unroll
  for (int mi = 0; mi < 2; ++mi)
    #pragma unroll
    for (int r = 0; r < 4; ++r){ mrow[mi][r] = -1e30f; lrow[mi][r] = 0.f; }

  int nchunk = q0 / 32 + 1;   // causal: only chunks with s0 <= q0+31
  for (int ch = 0; ch < nchunk; ++ch){
    int s0 = ch * 32;
    f32x4 S[2][2] = {};
    bf16x8 kf[2][2];
    #pragma unroll
    for (int ni = 0; ni < 2; ++ni)
      #pragma unroll
      for (int ks = 0; ks < 2; ++ks)
        kf[ni][ks] = *(const bf16x8*)(Kb + (size_t)(s0 + ni * 16 + c) * HSs + ks * 32 + g * 8);
    #pragma unroll
    for (int mi = 0; mi < 2; ++mi)
      #pragma unroll
      for (int ni = 0; ni < 2; ++ni)
        #pragma unroll
        for (int ks = 0; ks < 2; ++ks)
          S[mi][ni] = __builtin_amdgcn_mfma_f32_16x16x32_bf16(qf[mi][ks], kf[ni][ks], S[mi][ni], 0, 0, 0);

    if (ch == nchunk - 1){   // diagonal chunk: s0 == q0
      #pragma unroll
      for (int mi = 0; mi < 2; ++mi)
        #pragma unroll
        for (int ni = 0; ni < 2; ++ni)
          #pragma unroll
          for (int r = 0; r < 4; ++r){
            int tl = mi * 16 + g * 4 + r, sl = ni * 16 + c;
            if (sl > tl) S[mi][ni][r] = -1e30f;
          }
    }

    #pragma unroll
    for (int mi = 0; mi < 2; ++mi){
      #pragma unroll
      for (int r = 0; r < 4; ++r){
        float mx = fmaxf(S[mi][0][r], S[mi][1][r]);
        mx = fmaxf(mx, __shfl_xor(mx, 1));
        mx = fmaxf(mx, __shfl_xor(mx, 2));
        mx = fmaxf(mx, __shfl_xor(mx, 4));
        mx = fmaxf(mx, __shfl_xor(mx, 8));
        float mnew  = fmaxf(mrow[mi][r], mx);
        float alpha = __expf(mrow[mi][r] - mnew);
        float p0 = __expf(S[mi][0][r] - mnew);
        float p1 = __expf(S[mi][1][r] - mnew);
        float ps = p0 + p1;
        ps += __shfl_xor(ps, 1);
        ps += __shfl_xor(ps, 2);
        ps += __shfl_xor(ps, 4);
        ps += __shfl_xor(ps, 8);
        lrow[mi][r] = lrow[mi][r] * alpha + ps;
        mrow[mi][r] = mnew;
        #pragma unroll
        for (int dt = 0; dt < 4; ++dt) o[mi][dt][r] *= alpha;
        Pl[wid][mi * 16 + g * 4 + r][c]      = f2bf(p0);
        Pl[wid][mi * 16 + g * 4 + r][16 + c] = f2bf(p1);
      }
    }
    __builtin_amdgcn_sched_barrier(0);  // keep P writes before P reads (wave-private LDS, no s_barrier needed)

    bf16x8 vf[4];
    #pragma unroll
    for (int dt = 0; dt < 4; ++dt)
      #pragma unroll
      for (int j = 0; j < 8; ++j)
        vf[dt][j] = us2bf(Vb[(size_t)(s0 + g * 8 + j) * HSs + dt * 16 + c]);

    #pragma unroll
    for (int mi = 0; mi < 2; ++mi){
      bf16x8 pf = *(const bf16x8*)(&Pl[wid][mi * 16 + c][g * 8]);
      #pragma unroll
      for (int dt = 0; dt < 4; ++dt)
        o[mi][dt] = __builtin_amdgcn_mfma_f32_16x16x32_bf16(pf, vf[dt], o[mi][dt], 0, 0, 0);
    }
    __builtin_amdgcn_sched_barrier(0);
  }

  int b = bh >> 4, h = bh & 15;
  #pragma unroll
  for (int mi = 0; mi < 2; ++mi)
    #pragma unroll
    for (int dt = 0; dt < 4; ++dt)
      #pragma unroll
      for (int r = 0; r < 4; ++r){
        int t = q0 + mi * 16 + g * 4 + r;
        float val = o[mi][dt][r] / lrow[mi][r];
        attnb[((size_t)(b * Tt + t)) * Cc + h * HSs + dt * 16 + c] = f2bf(val);
      }
}

extern "C" void kernel_launch(void* const* d_in, const int* in_sizes, int n_in,
                              void* d_out, int out_size, void* d_ws, size_t ws_size,
                              hipStream_t stream) {
  (void)in_sizes; (void)n_in; (void)out_size; (void)ws_size;
  const float* x    = (const float*)d_in[0];
  // d_in[1] = mask (unused: causality computed analytically)
  const float* wq   = (const float*)d_in[2];
  const float* wk   = (const float*)d_in[3];
  const float* wv   = (const float*)d_in[4];
  const float* ln1g = (const float*)d_in[5];
  const float* ln1b = (const float*)d_in[6];
  const float* ln2g = (const float*)d_in[7];
  const float* ln2b = (const float*)d_in[8];
  const float* w1   = (const float*)d_in[9];
  const float* b1   = (const float*)d_in[10];
  const float* w2   = (const float*)d_in[11];
  const float* b2   = (const float*)d_in[12];
  float* out = (float*)d_out;

  char* ws = (char*)d_ws;
  const size_t SZ_ACT = (size_t)Bb * Tt * Cc * 2;       // 16 MB bf16 activation
  ushort* h1    = (ushort*)(ws);
  ushort* qb    = (ushort*)(ws + SZ_ACT);
  ushort* kb    = (ushort*)(ws + 2 * SZ_ACT);
  ushort* vb    = (ushort*)(ws + 3 * SZ_ACT);
  ushort* attnb = (ushort*)(ws + 4 * SZ_ACT);
  ushort* h2    = (ushort*)(ws + 5 * SZ_ACT);
  ushort* h3    = (ushort*)(ws + 6 * SZ_ACT);           // 64 MB: [8192, 4096] bf16
  char*   wsw   = ws + 6 * SZ_ACT + (size_t)Bb * Tt * 4 * Cc * 2;
  ushort* wqb = (ushort*)(wsw);
  ushort* wkb = (ushort*)(wsw + (size_t)Cc * Cc * 2);
  ushort* wvb = (ushort*)(wsw + 2 * (size_t)Cc * Cc * 2);
  ushort* w1b = (ushort*)(wsw + 3 * (size_t)Cc * Cc * 2);
  ushort* w2b = (ushort*)(wsw + 3 * (size_t)Cc * Cc * 2 + (size_t)4 * Cc * Cc * 2);

  // weight casts
  cast_bf16_kernel<<<dim3(Cc * Cc / 1024), 256, 0, stream>>>(wq, wqb);
  cast_bf16_kernel<<<dim3(Cc * Cc / 1024), 256, 0, stream>>>(wk, wkb);
  cast_bf16_kernel<<<dim3(Cc * Cc / 1024), 256, 0, stream>>>(wv, wvb);
  cast_bf16_kernel<<<dim3(4 * Cc * Cc / 1024), 256, 0, stream>>>(w1, w1b);
  cast_bf16_kernel<<<dim3(4 * Cc * Cc / 1024), 256, 0, stream>>>(w2, w2b);

  // LN1
  ln1_kernel<<<dim3(Bb * Tt), 256, 0, stream>>>(x, ln1g, ln1b, h1);

  // QKV projections (q pre-scaled by softmax 1/sqrt(64) = 0.125, exact in bf16)
  gemm_bt_kernel<0><<<dim3(8, 64), 256, 0, stream>>>(h1, wqb, Cc, Cc, qb, nullptr, nullptr, 0.125f);
  gemm_bt_kernel<0><<<dim3(8, 64), 256, 0, stream>>>(h1, wkb, Cc, Cc, kb, nullptr, nullptr, 1.0f);
  gemm_bt_kernel<0><<<dim3(8, 64), 256, 0, stream>>>(h1, wvb, Cc, Cc, vb, nullptr, nullptr, 1.0f);

  // attention
  attn_kernel<<<dim3(Tt / 128, Bb * Hh), 256, 0, stream>>>(qb, kb, vb, attnb);

  // LN2 (+ residual into d_out)
  ln2_kernel<<<dim3(Bb * Tt), 256, 0, stream>>>(x, attnb, ln2g, ln2b, out, h2);

  // FFN
  gemm_bt_kernel<1><<<dim3(32, 64), 256, 0, stream>>>(h2, w1b, 4 * Cc, Cc, h3, nullptr, b1, 1.0f);
  gemm_bt_kernel<2><<<dim3(8, 64), 256, 0, stream>>>(h3, w2b, Cc, 4 * Cc, nullptr, out, b2, 1.0f);
}

// Round 2
// 572.579 us; speedup vs baseline: 1.2161x; 1.2161x over previous
//
#include <hip/hip_runtime.h>
#include <stdint.h>

#define Bb 4
#define Tt 2048
#define Cc 1024
#define Hh 16
#define HSs 64

typedef __attribute__((ext_vector_type(8))) __bf16 bf16x8;
typedef __attribute__((ext_vector_type(4))) float f32x4;

__device__ __forceinline__ ushort f2bf(float f){
  union { float f; uint u; } c; c.f = f;
  uint r = c.u + 0x7fffu + ((c.u >> 16) & 1u);
  return (ushort)(r >> 16);
}
__device__ __forceinline__ float bf2f(ushort u){
  union { uint u; float f; } c; c.u = ((uint)u) << 16; return c.f;
}

// async global->LDS, 16B per lane. LDS dest must be wave-uniform base; HW adds lane*16.
__device__ __forceinline__ void gload16(const void* g, void* l){
  __builtin_amdgcn_global_load_lds(
      (__attribute__((address_space(1))) void*)(g),
      (__attribute__((address_space(3))) void*)(l), 16, 0, 0);
}

// ---------------- elementwise fp32 -> bf16 cast (weights) ----------------
__global__ __launch_bounds__(256) void cast_bf16_kernel(const float* __restrict__ in,
                                                        ushort* __restrict__ out){
  int i = (blockIdx.x * 256 + threadIdx.x) * 4;
  float4 v = *(const float4*)(in + i);
  ushort4 o; o.x = f2bf(v.x); o.y = f2bf(v.y); o.z = f2bf(v.z); o.w = f2bf(v.w);
  *(ushort4*)(out + i) = o;
}

// ---------------- LN1: h1 = LN(x) -> bf16 ----------------
__global__ __launch_bounds__(256) void ln1_kernel(const float* __restrict__ x,
    const float* __restrict__ gw, const float* __restrict__ bw,
    ushort* __restrict__ hout){
  int row = blockIdx.x, tid = threadIdx.x;
  size_t base = (size_t)row * Cc + tid * 4;
  float4 xv = *(const float4*)(x + base);
  float s  = xv.x + xv.y + xv.z + xv.w;
  float ss = xv.x*xv.x + xv.y*xv.y + xv.z*xv.z + xv.w*xv.w;
  #pragma unroll
  for (int off = 1; off < 64; off <<= 1){ s += __shfl_xor(s, off); ss += __shfl_xor(ss, off); }
  __shared__ float red[8];
  int wid = tid >> 6, lane = tid & 63;
  if (lane == 0){ red[wid] = s; red[4 + wid] = ss; }
  __syncthreads();
  s  = red[0] + red[1] + red[2] + red[3];
  ss = red[4] + red[5] + red[6] + red[7];
  float mu = s * (1.0f / Cc);
  float rstd = rsqrtf(ss * (1.0f / Cc) - mu * mu + 1e-5f);
  float4 gv = *(const float4*)(gw + tid * 4);
  float4 bv = *(const float4*)(bw + tid * 4);
  ushort4 o;
  o.x = f2bf((xv.x - mu) * rstd * gv.x + bv.x);
  o.y = f2bf((xv.y - mu) * rstd * gv.y + bv.y);
  o.z = f2bf((xv.z - mu) * rstd * gv.z + bv.z);
  o.w = f2bf((xv.w - mu) * rstd * gv.w + bv.w);
  *(ushort4*)(hout + base) = o;
}

// ---------------- LN2: x2 = x + attn (write to d_out), h2 = LN(x2) -> bf16 ----------------
__global__ __launch_bounds__(256) void ln2_kernel(const float* __restrict__ x,
    const ushort* __restrict__ attnb,
    const float* __restrict__ gw, const float* __restrict__ bw,
    float* __restrict__ x2, ushort* __restrict__ hout){
  int row = blockIdx.x, tid = threadIdx.x;
  size_t base = (size_t)row * Cc + tid * 4;
  float4 xv = *(const float4*)(x + base);
  ushort4 av = *(const ushort4*)(attnb + base);
  xv.x += bf2f(av.x); xv.y += bf2f(av.y); xv.z += bf2f(av.z); xv.w += bf2f(av.w);
  *(float4*)(x2 + base) = xv;
  float s  = xv.x + xv.y + xv.z + xv.w;
  float ss = xv.x*xv.x + xv.y*xv.y + xv.z*xv.z + xv.w*xv.w;
  #pragma unroll
  for (int off = 1; off < 64; off <<= 1){ s += __shfl_xor(s, off); ss += __shfl_xor(ss, off); }
  __shared__ float red[8];
  int wid = tid >> 6, lane = tid & 63;
  if (lane == 0){ red[wid] = s; red[4 + wid] = ss; }
  __syncthreads();
  s  = red[0] + red[1] + red[2] + red[3];
  ss = red[4] + red[5] + red[6] + red[7];
  float mu = s * (1.0f / Cc);
  float rstd = rsqrtf(ss * (1.0f / Cc) - mu * mu + 1e-5f);
  float4 gv = *(const float4*)(gw + tid * 4);
  float4 bv = *(const float4*)(bw + tid * 4);
  ushort4 o;
  o.x = f2bf((xv.x - mu) * rstd * gv.x + bv.x);
  o.y = f2bf((xv.y - mu) * rstd * gv.y + bv.y);
  o.z = f2bf((xv.z - mu) * rstd * gv.z + bv.z);
  o.w = f2bf((xv.w - mu) * rstd * gv.w + bv.w);
  *(ushort4*)(hout + base) = o;
}

// ---------------- GEMM: C[M,N] = A[M,K] (bf16) * W[N,K]^T (bf16), fp32 accum ----------------
// 128x128 tile, BK=64, 4 waves (2x2), 16x16x32 bf16 MFMA, 4x4 frags/wave.
// MODE 0: QKV scatter to [B,H,T,HS] bf16, scaled.  MODE 1: SiLU(acc+bias) -> bf16 row-major.
// MODE 2: acc + bias + of32[idx] -> of32[idx].     MODE 3: scatter TRANSPOSED to [B,H,HS,T].
template<int MODE>
__global__ __launch_bounds__(256) void gemm_bt_kernel(
    const ushort* __restrict__ A, const ushort* __restrict__ Bw,
    int N, int K,
    ushort* __restrict__ obf, float* __restrict__ of32,
    const float* __restrict__ bias, float scale)
{
  __shared__ __align__(16) ushort Asm[128 * 64];
  __shared__ __align__(16) ushort Bsm[128 * 64];
  int tid = threadIdx.x;
  int lane = tid & 63, wid = tid >> 6;
  int wm = wid >> 1, wn = wid & 1;
  int m0 = blockIdx.y * 128, n0 = blockIdx.x * 128;
  int srow = lane >> 3, schunk = lane & 7;
  int c = lane & 15, g = lane >> 4;
  f32x4 acc[4][4] = {};

  for (int k0 = 0; k0 < K; k0 += 64){
    #pragma unroll
    for (int it = 0; it < 4; ++it){
      int row = wid * 32 + it * 8 + srow;
      gload16(A  + (size_t)(m0 + row) * K + k0 + schunk * 8,
              Asm + (size_t)(wid * 32 + it * 8) * 64);
      gload16(Bw + (size_t)(n0 + row) * K + k0 + schunk * 8,
              Bsm + (size_t)(wid * 32 + it * 8) * 64);
    }
    __syncthreads();
    #pragma unroll
    for (int ks = 0; ks < 2; ++ks){
      bf16x8 af[4], bfr[4];
      #pragma unroll
      for (int mi = 0; mi < 4; ++mi)
        af[mi] = *(const bf16x8*)(Asm + (wm * 64 + mi * 16 + c) * 64 + ks * 32 + g * 8);
      #pragma unroll
      for (int ni = 0; ni < 4; ++ni)
        bfr[ni] = *(const bf16x8*)(Bsm + (wn * 64 + ni * 16 + c) * 64 + ks * 32 + g * 8);
      #pragma unroll
      for (int mi = 0; mi < 4; ++mi)
        #pragma unroll
        for (int ni = 0; ni < 4; ++ni)
          acc[mi][ni] = __builtin_amdgcn_mfma_f32_16x16x32_bf16(af[mi], bfr[ni], acc[mi][ni], 0, 0, 0);
    }
    __syncthreads();
  }

  #pragma unroll
  for (int mi = 0; mi < 4; ++mi){
    #pragma unroll
    for (int ni = 0; ni < 4; ++ni){
      #pragma unroll
      for (int r = 0; r < 4; ++r){
        float v = acc[mi][ni][r];
        int m = m0 + wm * 64 + mi * 16 + g * 4 + r;
        int n = n0 + wn * 64 + ni * 16 + c;
        if (MODE == 0){
          v *= scale;
          int b = m >> 11, t = m & (Tt - 1);
          int h = n >> 6,  d = n & 63;
          obf[(((size_t)(b * Hh + h)) * Tt + t) * HSs + d] = f2bf(v);
        } else if (MODE == 1){
          v += bias[n];
          float sv = v / (1.0f + __expf(-v));   // SiLU
          obf[(size_t)m * N + n] = f2bf(sv);
        } else if (MODE == 2){
          size_t idx = (size_t)m * Cc + n;
          of32[idx] = of32[idx] + v + bias[n];  // x2 + ff
        } else {  // MODE 3: V^T scatter [B,H,HS,T]
          int b = m >> 11, t = m & (Tt - 1);
          int h = n >> 6,  d = n & 63;
          obf[(((size_t)(b * Hh + h)) * HSs + d) * Tt + t] = f2bf(v);
        }
      }
    }
  }
}

// ---------------- causal flash attention ----------------
// 1 wave per block, 32 q-rows per wave, 64-kv chunks, V pre-transposed [B,H,HS,T].
// grid (T/32, B*H), 64 threads. tile order reversed (longest first) for load balance.
__global__ __launch_bounds__(64) void attn_kernel(
    const ushort* __restrict__ q, const ushort* __restrict__ k,
    const ushort* __restrict__ vt, ushort* __restrict__ attnb)
{
  __shared__ __align__(16) ushort Pl[32 * 64];   // P tile, XOR-swizzled rows
  int bh   = blockIdx.y;
  int tile = gridDim.x - 1 - blockIdx.x;         // longest-work-first
  int lane = threadIdx.x;
  int g = lane >> 4, c = lane & 15;
  int q0 = tile * 32;
  const ushort* Qb = q  + (size_t)bh * Tt * HSs;
  const ushort* Kb = k  + (size_t)bh * Tt * HSs;
  const ushort* Vt = vt + (size_t)bh * HSs * Tt;

  bf16x8 qf[2][2];   // q pre-scaled by 1/8 at projection time
  #pragma unroll
  for (int mi = 0; mi < 2; ++mi)
    #pragma unroll
    for (int ks = 0; ks < 2; ++ks)
      qf[mi][ks] = *(const bf16x8*)(Qb + (size_t)(q0 + mi * 16 + c) * HSs + ks * 32 + g * 8);

  f32x4 o[2][4] = {};
  float mrow[2][4], lrow[2][4];
  #pragma unroll
  for (int mi = 0; mi < 2; ++mi)
    #pragma unroll
    for (int r = 0; r < 4; ++r){ mrow[mi][r] = -1e30f; lrow[mi][r] = 0.f; }

  int nch = tile / 2 + 1;                        // 64-wide chunks; last contains diagonal
  for (int ch = 0; ch < nch; ++ch){
    int s0 = ch * 64;
    f32x4 S[2][4] = {};
    bf16x8 kf[4][2];
    #pragma unroll
    for (int ni = 0; ni < 4; ++ni)
      #pragma unroll
      for (int ks = 0; ks < 2; ++ks)
        kf[ni][ks] = *(const bf16x8*)(Kb + (size_t)(s0 + ni * 16 + c) * HSs + ks * 32 + g * 8);
    #pragma unroll
    for (int mi = 0; mi < 2; ++mi)
      #pragma unroll
      for (int ni = 0; ni < 4; ++ni)
        #pragma unroll
        for (int ks = 0; ks < 2; ++ks)
          S[mi][ni] = __builtin_amdgcn_mfma_f32_16x16x32_bf16(qf[mi][ks], kf[ni][ks], S[mi][ni], 0, 0, 0);

    if (ch == nch - 1){   // diagonal chunk
      #pragma unroll
      for (int mi = 0; mi < 2; ++mi)
        #pragma unroll
        for (int ni = 0; ni < 4; ++ni)
          #pragma unroll
          for (int r = 0; r < 4; ++r){
            int tl = q0 + mi * 16 + g * 4 + r, sl = s0 + ni * 16 + c;
            if (sl > tl) S[mi][ni][r] = -1e30f;
          }
    }

    #pragma unroll
    for (int mi = 0; mi < 2; ++mi){
      #pragma unroll
      for (int r = 0; r < 4; ++r){
        float mx = fmaxf(fmaxf(S[mi][0][r], S[mi][1][r]), fmaxf(S[mi][2][r], S[mi][3][r]));
        mx = fmaxf(mx, __shfl_xor(mx, 1));
        mx = fmaxf(mx, __shfl_xor(mx, 2));
        mx = fmaxf(mx, __shfl_xor(mx, 4));
        mx = fmaxf(mx, __shfl_xor(mx, 8));
        float mnew  = fmaxf(mrow[mi][r], mx);
        float alpha = __expf(mrow[mi][r] - mnew);
        float p[4], ps = 0.f;
        #pragma unroll
        for (int ni = 0; ni < 4; ++ni){ p[ni] = __expf(S[mi][ni][r] - mnew); ps += p[ni]; }
        ps += __shfl_xor(ps, 1);
        ps += __shfl_xor(ps, 2);
        ps += __shfl_xor(ps, 4);
        ps += __shfl_xor(ps, 8);
        lrow[mi][r] = lrow[mi][r] * alpha + ps;
        mrow[mi][r] = mnew;
        #pragma unroll
        for (int dt = 0; dt < 4; ++dt) o[mi][dt][r] *= alpha;
        int row = mi * 16 + g * 4 + r, sw = (row & 7) << 3;
        #pragma unroll
        for (int ni = 0; ni < 4; ++ni)
          Pl[row * 64 + ((ni * 16 + c) ^ sw)] = f2bf(p[ni]);
      }
    }
    __builtin_amdgcn_sched_barrier(0);  // wave-private LDS: keep P writes before reads

    bf16x8 vf[4][2];
    #pragma unroll
    for (int dt = 0; dt < 4; ++dt)
      #pragma unroll
      for (int ks = 0; ks < 2; ++ks)
        vf[dt][ks] = *(const bf16x8*)(Vt + (size_t)(dt * 16 + c) * Tt + s0 + ks * 32 + g * 8);

    #pragma unroll
    for (int mi = 0; mi < 2; ++mi){
      int prow = mi * 16 + c, sw = (prow & 7) << 3;
      #pragma unroll
      for (int ks = 0; ks < 2; ++ks){
        bf16x8 pf = *(const bf16x8*)(Pl + prow * 64 + ((ks * 32 + g * 8) ^ sw));
        #pragma unroll
        for (int dt = 0; dt < 4; ++dt)
          o[mi][dt] = __builtin_amdgcn_mfma_f32_16x16x32_bf16(pf, vf[dt][ks], o[mi][dt], 0, 0, 0);
      }
    }
    __builtin_amdgcn_sched_barrier(0);
  }

  int b = bh >> 4, h = bh & 15;
  #pragma unroll
  for (int mi = 0; mi < 2; ++mi)
    #pragma unroll
    for (int dt = 0; dt < 4; ++dt)
      #pragma unroll
      for (int r = 0; r < 4; ++r){
        int t = q0 + mi * 16 + g * 4 + r;
        float val = o[mi][dt][r] / lrow[mi][r];
        attnb[((size_t)(b * Tt + t)) * Cc + h * HSs + dt * 16 + c] = f2bf(val);
      }
}

extern "C" void kernel_launch(void* const* d_in, const int* in_sizes, int n_in,
                              void* d_out, int out_size, void* d_ws, size_t ws_size,
                              hipStream_t stream) {
  (void)in_sizes; (void)n_in; (void)out_size; (void)ws_size;
  const float* x    = (const float*)d_in[0];
  const float* wq   = (const float*)d_in[2];
  const float* wk   = (const float*)d_in[3];
  const float* wv   = (const float*)d_in[4];
  const float* ln1g = (const float*)d_in[5];
  const float* ln1b = (const float*)d_in[6];
  const float* ln2g = (const float*)d_in[7];
  const float* ln2b = (const float*)d_in[8];
  const float* w1   = (const float*)d_in[9];
  const float* b1   = (const float*)d_in[10];
  const float* w2   = (const float*)d_in[11];
  const float* b2   = (const float*)d_in[12];
  float* out = (float*)d_out;

  char* ws = (char*)d_ws;
  const size_t SZ_ACT = (size_t)Bb * Tt * Cc * 2;
  ushort* h1    = (ushort*)(ws);
  ushort* qb    = (ushort*)(ws + SZ_ACT);
  ushort* kb    = (ushort*)(ws + 2 * SZ_ACT);
  ushort* vb    = (ushort*)(ws + 3 * SZ_ACT);   // V^T layout [B,H,HS,T]
  ushort* attnb = (ushort*)(ws + 4 * SZ_ACT);
  ushort* h2    = (ushort*)(ws + 5 * SZ_ACT);
  ushort* h3    = (ushort*)(ws + 6 * SZ_ACT);
  char*   wsw   = ws + 6 * SZ_ACT + (size_t)Bb * Tt * 4 * Cc * 2;
  ushort* wqb = (ushort*)(wsw);
  ushort* wkb = (ushort*)(wsw + (size_t)Cc * Cc * 2);
  ushort* wvb = (ushort*)(wsw + 2 * (size_t)Cc * Cc * 2);
  ushort* w1b = (ushort*)(wsw + 3 * (size_t)Cc * Cc * 2);
  ushort* w2b = (ushort*)(wsw + 3 * (size_t)Cc * Cc * 2 + (size_t)4 * Cc * Cc * 2);

  cast_bf16_kernel<<<dim3(Cc * Cc / 1024), 256, 0, stream>>>(wq, wqb);
  cast_bf16_kernel<<<dim3(Cc * Cc / 1024), 256, 0, stream>>>(wk, wkb);
  cast_bf16_kernel<<<dim3(Cc * Cc / 1024), 256, 0, stream>>>(wv, wvb);
  cast_bf16_kernel<<<dim3(4 * Cc * Cc / 1024), 256, 0, stream>>>(w1, w1b);
  cast_bf16_kernel<<<dim3(4 * Cc * Cc / 1024), 256, 0, stream>>>(w2, w2b);

  ln1_kernel<<<dim3(Bb * Tt), 256, 0, stream>>>(x, ln1g, ln1b, h1);

  // QKV projections (q pre-scaled by 1/sqrt(64) = 0.125; V written transposed)
  gemm_bt_kernel<0><<<dim3(8, 64), 256, 0, stream>>>(h1, wqb, Cc, Cc, qb, nullptr, nullptr, 0.125f);
  gemm_bt_kernel<0><<<dim3(8, 64), 256, 0, stream>>>(h1, wkb, Cc, Cc, kb, nullptr, nullptr, 1.0f);
  gemm_bt_kernel<3><<<dim3(8, 64), 256, 0, stream>>>(h1, wvb, Cc, Cc, vb, nullptr, nullptr, 1.0f);

  attn_kernel<<<dim3(Tt / 32, Bb * Hh), 64, 0, stream>>>(qb, kb, vb, attnb);

  ln2_kernel<<<dim3(Bb * Tt), 256, 0, stream>>>(x, attnb, ln2g, ln2b, out, h2);

  gemm_bt_kernel<1><<<dim3(32, 64), 256, 0, stream>>>(h2, w1b, 4 * Cc, Cc, h3, nullptr, b1, 1.0f);
  gemm_bt_kernel<2><<<dim3(8, 64), 256, 0, stream>>>(h3, w2b, Cc, 4 * Cc, nullptr, out, b2, 1.0f);
}

// Round 3
// 537.909 us; speedup vs baseline: 1.2945x; 1.0645x over previous
//
#include <hip/hip_runtime.h>
#include <stdint.h>

#define Bb 4
#define Tt 2048
#define Cc 1024
#define Hh 16
#define HSs 64

typedef __attribute__((ext_vector_type(8))) __bf16 bf16x8;
typedef __attribute__((ext_vector_type(4))) float f32x4;

__device__ __forceinline__ ushort f2bf(float f){
  union { float f; uint u; } c; c.f = f;
  uint r = c.u + 0x7fffu + ((c.u >> 16) & 1u);
  return (ushort)(r >> 16);
}
__device__ __forceinline__ float bf2f(ushort u){
  union { uint u; float f; } c; c.u = ((uint)u) << 16; return c.f;
}

// async global->LDS, 16B per lane. LDS dest wave-uniform base; HW adds lane*16.
__device__ __forceinline__ void gload16(const void* g, void* l){
  __builtin_amdgcn_global_load_lds(
      (__attribute__((address_space(1))) void*)(g),
      (__attribute__((address_space(3))) void*)(l), 16, 0, 0);
}

// ---------------- elementwise fp32 -> bf16 cast (weights) ----------------
__global__ __launch_bounds__(256) void cast_bf16_kernel(const float* __restrict__ in,
                                                        ushort* __restrict__ out){
  int i = (blockIdx.x * 256 + threadIdx.x) * 4;
  float4 v = *(const float4*)(in + i);
  ushort4 o; o.x = f2bf(v.x); o.y = f2bf(v.y); o.z = f2bf(v.z); o.w = f2bf(v.w);
  *(ushort4*)(out + i) = o;
}

// ---------------- LN1 ----------------
__global__ __launch_bounds__(256) void ln1_kernel(const float* __restrict__ x,
    const float* __restrict__ gw, const float* __restrict__ bw,
    ushort* __restrict__ hout){
  int row = blockIdx.x, tid = threadIdx.x;
  size_t base = (size_t)row * Cc + tid * 4;
  float4 xv = *(const float4*)(x + base);
  float s  = xv.x + xv.y + xv.z + xv.w;
  float ss = xv.x*xv.x + xv.y*xv.y + xv.z*xv.z + xv.w*xv.w;
  #pragma unroll
  for (int off = 1; off < 64; off <<= 1){ s += __shfl_xor(s, off); ss += __shfl_xor(ss, off); }
  __shared__ float red[8];
  int wid = tid >> 6, lane = tid & 63;
  if (lane == 0){ red[wid] = s; red[4 + wid] = ss; }
  __syncthreads();
  s  = red[0] + red[1] + red[2] + red[3];
  ss = red[4] + red[5] + red[6] + red[7];
  float mu = s * (1.0f / Cc);
  float rstd = rsqrtf(ss * (1.0f / Cc) - mu * mu + 1e-5f);
  float4 gv = *(const float4*)(gw + tid * 4);
  float4 bv = *(const float4*)(bw + tid * 4);
  ushort4 o;
  o.x = f2bf((xv.x - mu) * rstd * gv.x + bv.x);
  o.y = f2bf((xv.y - mu) * rstd * gv.y + bv.y);
  o.z = f2bf((xv.z - mu) * rstd * gv.z + bv.z);
  o.w = f2bf((xv.w - mu) * rstd * gv.w + bv.w);
  *(ushort4*)(hout + base) = o;
}

// ---------------- LN2: x2 = x + attn -> d_out, h2 = LN(x2) -> bf16 ----------------
__global__ __launch_bounds__(256) void ln2_kernel(const float* __restrict__ x,
    const ushort* __restrict__ attnb,
    const float* __restrict__ gw, const float* __restrict__ bw,
    float* __restrict__ x2, ushort* __restrict__ hout){
  int row = blockIdx.x, tid = threadIdx.x;
  size_t base = (size_t)row * Cc + tid * 4;
  float4 xv = *(const float4*)(x + base);
  ushort4 av = *(const ushort4*)(attnb + base);
  xv.x += bf2f(av.x); xv.y += bf2f(av.y); xv.z += bf2f(av.z); xv.w += bf2f(av.w);
  *(float4*)(x2 + base) = xv;
  float s  = xv.x + xv.y + xv.z + xv.w;
  float ss = xv.x*xv.x + xv.y*xv.y + xv.z*xv.z + xv.w*xv.w;
  #pragma unroll
  for (int off = 1; off < 64; off <<= 1){ s += __shfl_xor(s, off); ss += __shfl_xor(ss, off); }
  __shared__ float red[8];
  int wid = tid >> 6, lane = tid & 63;
  if (lane == 0){ red[wid] = s; red[4 + wid] = ss; }
  __syncthreads();
  s  = red[0] + red[1] + red[2] + red[3];
  ss = red[4] + red[5] + red[6] + red[7];
  float mu = s * (1.0f / Cc);
  float rstd = rsqrtf(ss * (1.0f / Cc) - mu * mu + 1e-5f);
  float4 gv = *(const float4*)(gw + tid * 4);
  float4 bv = *(const float4*)(bw + tid * 4);
  ushort4 o;
  o.x = f2bf((xv.x - mu) * rstd * gv.x + bv.x);
  o.y = f2bf((xv.y - mu) * rstd * gv.y + bv.y);
  o.z = f2bf((xv.z - mu) * rstd * gv.z + bv.z);
  o.w = f2bf((xv.w - mu) * rstd * gv.w + bv.w);
  *(ushort4*)(hout + base) = o;
}

// ---------------- GEMM: C[M,N] = A[M,K] * W[N,K]^T (bf16, fp32 accum) ----------------
// 128x128 tile, BK=64, 4 waves (2x2), 16x16x32 MFMA, 4x4 frags/wave.
// MODE 0: fused QKV scatter (N=3072): q scaled 0.125 [B,H,T,HS]; k [B,H,T,HS]; v TRANSPOSED [B,H,HS,T].
// MODE 1: SiLU(acc+bias) -> bf16 row-major.  MODE 2: of32[idx] += acc + bias (residual).
template<int MODE>
__global__ __launch_bounds__(256) void gemm_bt_kernel(
    const ushort* __restrict__ A, const ushort* __restrict__ Bw,
    int N, int K,
    ushort* __restrict__ obf, float* __restrict__ of32,
    const float* __restrict__ bias, float scale)
{
  __shared__ __align__(16) ushort Asm[128 * 64];
  __shared__ __align__(16) ushort Bsm[128 * 64];
  int tid = threadIdx.x;
  int lane = tid & 63, wid = tid >> 6;
  int wm = wid >> 1, wn = wid & 1;
  int m0 = blockIdx.y * 128, n0 = blockIdx.x * 128;
  int srow = lane >> 3, schunk = lane & 7;
  int c = lane & 15, g = lane >> 4;
  f32x4 acc[4][4] = {};

  for (int k0 = 0; k0 < K; k0 += 64){
    #pragma unroll
    for (int it = 0; it < 4; ++it){
      int row = wid * 32 + it * 8 + srow;
      gload16(A  + (size_t)(m0 + row) * K + k0 + schunk * 8,
              Asm + (size_t)(wid * 32 + it * 8) * 64);
      gload16(Bw + (size_t)(n0 + row) * K + k0 + schunk * 8,
              Bsm + (size_t)(wid * 32 + it * 8) * 64);
    }
    __syncthreads();
    #pragma unroll
    for (int ks = 0; ks < 2; ++ks){
      bf16x8 af[4], bfr[4];
      #pragma unroll
      for (int mi = 0; mi < 4; ++mi)
        af[mi] = *(const bf16x8*)(Asm + (wm * 64 + mi * 16 + c) * 64 + ks * 32 + g * 8);
      #pragma unroll
      for (int ni = 0; ni < 4; ++ni)
        bfr[ni] = *(const bf16x8*)(Bsm + (wn * 64 + ni * 16 + c) * 64 + ks * 32 + g * 8);
      #pragma unroll
      for (int mi = 0; mi < 4; ++mi)
        #pragma unroll
        for (int ni = 0; ni < 4; ++ni)
          acc[mi][ni] = __builtin_amdgcn_mfma_f32_16x16x32_bf16(af[mi], bfr[ni], acc[mi][ni], 0, 0, 0);
    }
    __syncthreads();
  }

  #pragma unroll
  for (int mi = 0; mi < 4; ++mi){
    #pragma unroll
    for (int ni = 0; ni < 4; ++ni){
      #pragma unroll
      for (int r = 0; r < 4; ++r){
        float v = acc[mi][ni][r];
        int m = m0 + wm * 64 + mi * 16 + g * 4 + r;
        int n = n0 + wn * 64 + ni * 16 + c;
        if (MODE == 0){
          int which = n >> 10;
          int nn = n & 1023;
          int b = m >> 11, t = m & (Tt - 1);
          int h = nn >> 6, d = nn & 63;
          float vv = (which == 0) ? v * 0.125f : v;   // fold softmax scale into q
          size_t base = (size_t)which * (size_t)(Bb * Tt * Cc);
          size_t idx = (which == 2)
              ? ((((size_t)(b * Hh + h)) * HSs + d) * Tt + t)     // V^T [B,H,HS,T]
              : ((((size_t)(b * Hh + h)) * Tt + t) * HSs + d);    // Q,K [B,H,T,HS]
          obf[base + idx] = f2bf(vv);
        } else if (MODE == 1){
          v += bias[n];
          float sv = v / (1.0f + __expf(-v));   // SiLU
          obf[(size_t)m * N + n] = f2bf(sv);
        } else {
          size_t idx = (size_t)m * Cc + n;
          of32[idx] = of32[idx] + v + bias[n];  // x2 + ff
        }
      }
    }
  }
}

// ---------------- causal flash attention ----------------
// Block: 256 thr = 4 waves, 128 q-rows (32/wave). KV chunks of 64 staged into
// double-buffered XOR-swizzled LDS via global_load_lds (shared by all 4 waves).
// Softmax: defer-max (THR=8) + lane-partial denominator (no per-chunk shfl reduce).
__global__ __launch_bounds__(256, 3) void attn_kernel(
    const ushort* __restrict__ q, const ushort* __restrict__ k,
    const ushort* __restrict__ vt, ushort* __restrict__ attnb)
{
  __shared__ __align__(16) ushort Ksm[2][64 * 64];
  __shared__ __align__(16) ushort Vsm[2][64 * 64];
  __shared__ __align__(16) ushort Pl[4][32 * 64];

  int bh  = blockIdx.y;
  int qb  = gridDim.x - 1 - blockIdx.x;          // longest-work-first
  int tid = threadIdx.x, wid = tid >> 6, lane = tid & 63;
  int g = lane >> 4, c = lane & 15;
  int q0 = qb * 128 + wid * 32;
  const ushort* Qb = q  + (size_t)bh * Tt * HSs;
  const ushort* Kb = k  + (size_t)bh * Tt * HSs;
  const ushort* Vt = vt + (size_t)bh * HSs * Tt;
  char* Pw = (char*)&Pl[wid][0];

  // stage K/V chunk into LDS: linear dest + inverse-swizzled global source (G21).
  // swizzle: LDS[row*128 + b] = src[row][b ^ ((row&7)<<4)]
  auto stageKV = [&](int bsel, int s0){
    #pragma unroll
    for (int half = 0; half < 2; ++half){
      int i = wid + half * 4;                    // 0..7
      int row = i * 8 + (lane >> 3);             // 0..63
      int col = ((lane & 7) ^ (row & 7)) * 8;    // elements
      gload16(Kb + (size_t)(s0 + row) * HSs + col, &Ksm[bsel][i * 512]);
      gload16(Vt + (size_t)row * Tt + s0 + col,    &Vsm[bsel][i * 512]);
    }
  };

  bf16x8 qf[2][2];
  #pragma unroll
  for (int mi = 0; mi < 2; ++mi)
    #pragma unroll
    for (int ks = 0; ks < 2; ++ks)
      qf[mi][ks] = *(const bf16x8*)(Qb + (size_t)(q0 + mi * 16 + c) * HSs + ks * 32 + g * 8);

  f32x4 o[2][4] = {};
  float mrow[2][4], lpart[2][4];
  #pragma unroll
  for (int mi = 0; mi < 2; ++mi)
    #pragma unroll
    for (int r = 0; r < 4; ++r){ mrow[mi][r] = -1e30f; lpart[mi][r] = 0.f; }

  int nch    = qb * 2 + 2;                       // chunks staged by the block
  int ccount = qb * 2 + 1 + (wid >> 1);          // chunks this wave computes

  stageKV(0, 0);
  asm volatile("s_waitcnt vmcnt(0)" ::: "memory");
  __builtin_amdgcn_s_barrier();

  for (int ch = 0; ch < nch; ++ch){
    int buf = ch & 1;
    if (ch + 1 < nch) stageKV(buf ^ 1, (ch + 1) * 64);   // prefetch next chunk

    if (ch < ccount){
      int s0 = ch * 64;
      const char* Kbuf = (const char*)&Ksm[buf][0];
      const char* Vbuf = (const char*)&Vsm[buf][0];

      // ---- QK^T ----
      f32x4 S[2][4] = {};
      bf16x8 kf[4][2];
      #pragma unroll
      for (int ni = 0; ni < 4; ++ni)
        #pragma unroll
        for (int ks = 0; ks < 2; ++ks)
          kf[ni][ks] = *(const bf16x8*)(Kbuf + (ni * 16 + c) * 128 + (((ks * 4 + g) ^ (c & 7)) << 4));
      #pragma unroll
      for (int mi = 0; mi < 2; ++mi)
        #pragma unroll
        for (int ni = 0; ni < 4; ++ni)
          #pragma unroll
          for (int ks = 0; ks < 2; ++ks)
            S[mi][ni] = __builtin_amdgcn_mfma_f32_16x16x32_bf16(qf[mi][ks], kf[ni][ks], S[mi][ni], 0, 0, 0);

      if (s0 + 63 > q0){   // diagonal chunk: apply causal mask
        #pragma unroll
        for (int mi = 0; mi < 2; ++mi)
          #pragma unroll
          for (int ni = 0; ni < 4; ++ni)
            #pragma unroll
            for (int r = 0; r < 4; ++r){
              int tl = q0 + mi * 16 + g * 4 + r, sl = s0 + ni * 16 + c;
              if (sl > tl) S[mi][ni][r] = -1e30f;
            }
      }

      // ---- softmax: defer-max + lane-partial denominator ----
      float lmax[2][4], worst = -1e30f;
      #pragma unroll
      for (int mi = 0; mi < 2; ++mi)
        #pragma unroll
        for (int r = 0; r < 4; ++r){
          float a0 = fmaxf(S[mi][0][r], S[mi][1][r]);
          float a1 = fmaxf(S[mi][2][r], S[mi][3][r]);
          lmax[mi][r] = fmaxf(a0, a1);
          worst = fmaxf(worst, lmax[mi][r] - mrow[mi][r]);
        }
      if (!__all(worst <= 8.0f)){                // rare: true max grew too much
        #pragma unroll
        for (int mi = 0; mi < 2; ++mi)
          #pragma unroll
          for (int r = 0; r < 4; ++r){
            float mx = lmax[mi][r];
            mx = fmaxf(mx, __shfl_xor(mx, 1));
            mx = fmaxf(mx, __shfl_xor(mx, 2));
            mx = fmaxf(mx, __shfl_xor(mx, 4));
            mx = fmaxf(mx, __shfl_xor(mx, 8));
            float mnew  = fmaxf(mrow[mi][r], mx);
            float alpha = __expf(mrow[mi][r] - mnew);
            lpart[mi][r] *= alpha;
            #pragma unroll
            for (int dt = 0; dt < 4; ++dt) o[mi][dt][r] *= alpha;
            mrow[mi][r] = mnew;
          }
      }
      #pragma unroll
      for (int mi = 0; mi < 2; ++mi)
        #pragma unroll
        for (int r = 0; r < 4; ++r){
          int row = mi * 16 + g * 4 + r;
          float mb = mrow[mi][r] * 1.44269504f;
          float p[4];
          #pragma unroll
          for (int ni = 0; ni < 4; ++ni){
            p[ni] = exp2f(__builtin_fmaf(S[mi][ni][r], 1.44269504f, -mb));
            *(ushort*)(Pw + row * 128 + (((ni * 32 + 2 * c) ^ ((row & 7) << 4)))) = f2bf(p[ni]);
          }
          lpart[mi][r] += (p[0] + p[1]) + (p[2] + p[3]);
        }
      __builtin_amdgcn_sched_barrier(0);   // wave-private P: writes before reads

      // ---- PV ----
      bf16x8 vf[4][2];
      #pragma unroll
      for (int dt = 0; dt < 4; ++dt)
        #pragma unroll
        for (int ks = 0; ks < 2; ++ks)
          vf[dt][ks] = *(const bf16x8*)(Vbuf + (dt * 16 + c) * 128 + (((ks * 4 + g) ^ (c & 7)) << 4));
      #pragma unroll
      for (int mi = 0; mi < 2; ++mi){
        #pragma unroll
        for (int ks = 0; ks < 2; ++ks){
          bf16x8 pf = *(const bf16x8*)(Pw + (mi * 16 + c) * 128 + ((((ks * 4 + g) ^ (c & 7)) << 4)));
          #pragma unroll
          for (int dt = 0; dt < 4; ++dt)
            o[mi][dt] = __builtin_amdgcn_mfma_f32_16x16x32_bf16(pf, vf[dt][ks], o[mi][dt], 0, 0, 0);
        }
      }
      __builtin_amdgcn_sched_barrier(0);
    }

    asm volatile("s_waitcnt vmcnt(0) lgkmcnt(0)" ::: "memory");
    __builtin_amdgcn_s_barrier();
  }

  // final denominator reduce (once) + write
  float linv[2][4];
  #pragma unroll
  for (int mi = 0; mi < 2; ++mi)
    #pragma unroll
    for (int r = 0; r < 4; ++r){
      float ls = lpart[mi][r];
      ls += __shfl_xor(ls, 1);
      ls += __shfl_xor(ls, 2);
      ls += __shfl_xor(ls, 4);
      ls += __shfl_xor(ls, 8);
      linv[mi][r] = 1.0f / ls;
    }
  int b = bh >> 4, h = bh & 15;
  #pragma unroll
  for (int mi = 0; mi < 2; ++mi)
    #pragma unroll
    for (int dt = 0; dt < 4; ++dt)
      #pragma unroll
      for (int r = 0; r < 4; ++r){
        int t = q0 + mi * 16 + g * 4 + r;
        attnb[((size_t)(b * Tt + t)) * Cc + h * HSs + dt * 16 + c] = f2bf(o[mi][dt][r] * linv[mi][r]);
      }
}

extern "C" void kernel_launch(void* const* d_in, const int* in_sizes, int n_in,
                              void* d_out, int out_size, void* d_ws, size_t ws_size,
                              hipStream_t stream) {
  (void)in_sizes; (void)n_in; (void)out_size; (void)ws_size;
  const float* x    = (const float*)d_in[0];
  const float* wq   = (const float*)d_in[2];
  const float* wk   = (const float*)d_in[3];
  const float* wv   = (const float*)d_in[4];
  const float* ln1g = (const float*)d_in[5];
  const float* ln1b = (const float*)d_in[6];
  const float* ln2g = (const float*)d_in[7];
  const float* ln2b = (const float*)d_in[8];
  const float* w1   = (const float*)d_in[9];
  const float* b1   = (const float*)d_in[10];
  const float* w2   = (const float*)d_in[11];
  const float* b2   = (const float*)d_in[12];
  float* out = (float*)d_out;

  char* ws = (char*)d_ws;
  const size_t SZ_ACT = (size_t)Bb * Tt * Cc * 2;
  ushort* h1    = (ushort*)(ws);
  ushort* qbuf  = (ushort*)(ws + SZ_ACT);       // q,k,vT contiguous (fused QKV epilogue)
  ushort* kbuf  = (ushort*)(ws + 2 * SZ_ACT);
  ushort* vbuf  = (ushort*)(ws + 3 * SZ_ACT);   // V^T [B,H,HS,T]
  ushort* attnb = (ushort*)(ws + 4 * SZ_ACT);
  ushort* h2    = (ushort*)(ws + 5 * SZ_ACT);
  ushort* h3    = (ushort*)(ws + 6 * SZ_ACT);
  char*   wsw   = ws + 6 * SZ_ACT + (size_t)Bb * Tt * 4 * Cc * 2;
  ushort* wqb = (ushort*)(wsw);                 // wq,wk,wv contiguous -> [3072,1024]
  ushort* wkb = (ushort*)(wsw + (size_t)Cc * Cc * 2);
  ushort* wvb = (ushort*)(wsw + 2 * (size_t)Cc * Cc * 2);
  ushort* w1b = (ushort*)(wsw + 3 * (size_t)Cc * Cc * 2);
  ushort* w2b = (ushort*)(wsw + 3 * (size_t)Cc * Cc * 2 + (size_t)4 * Cc * Cc * 2);

  cast_bf16_kernel<<<dim3(Cc * Cc / 1024), 256, 0, stream>>>(wq, wqb);
  cast_bf16_kernel<<<dim3(Cc * Cc / 1024), 256, 0, stream>>>(wk, wkb);
  cast_bf16_kernel<<<dim3(Cc * Cc / 1024), 256, 0, stream>>>(wv, wvb);
  cast_bf16_kernel<<<dim3(4 * Cc * Cc / 1024), 256, 0, stream>>>(w1, w1b);
  cast_bf16_kernel<<<dim3(4 * Cc * Cc / 1024), 256, 0, stream>>>(w2, w2b);

  ln1_kernel<<<dim3(Bb * Tt), 256, 0, stream>>>(x, ln1g, ln1b, h1);

  // fused QKV projection: W = [wq;wk;wv] contiguous [3072,1024]
  gemm_bt_kernel<0><<<dim3(24, 64), 256, 0, stream>>>(h1, wqb, 3 * Cc, Cc, qbuf, nullptr, nullptr, 0.125f);

  attn_kernel<<<dim3(Tt / 128, Bb * Hh), 256, 0, stream>>>(qbuf, kbuf, vbuf, attnb);

  ln2_kernel<<<dim3(Bb * Tt), 256, 0, stream>>>(x, attnb, ln2g, ln2b, out, h2);

  gemm_bt_kernel<1><<<dim3(32, 64), 256, 0, stream>>>(h2, w1b, 4 * Cc, Cc, h3, nullptr, b1, 1.0f);
  gemm_bt_kernel<2><<<dim3(8, 64), 256, 0, stream>>>(h3, w2b, Cc, 4 * Cc, nullptr, out, b2, 1.0f);
}

// Round 4
// 494.015 us; speedup vs baseline: 1.4095x; 1.0889x over previous
//
#include <hip/hip_runtime.h>
#include <stdint.h>

#define Bb 4
#define Tt 2048
#define Cc 1024
#define Hh 16
#define HSs 64

typedef __attribute__((ext_vector_type(8))) __bf16 bf16x8;
typedef __attribute__((ext_vector_type(4))) float f32x4;

__device__ __forceinline__ ushort f2bf(float f){
  union { float f; uint u; } c; c.f = f;
  uint r = c.u + 0x7fffu + ((c.u >> 16) & 1u);
  return (ushort)(r >> 16);
}
__device__ __forceinline__ float bf2f(ushort u){
  union { uint u; float f; } c; c.u = ((uint)u) << 16; return c.f;
}

// async global->LDS, 16B per lane. LDS dest wave-uniform base; HW adds lane*16.
__device__ __forceinline__ void gload16(const void* g, void* l){
  __builtin_amdgcn_global_load_lds(
      (__attribute__((address_space(1))) void*)(g),
      (__attribute__((address_space(3))) void*)(l), 16, 0, 0);
}

// ---------------- elementwise fp32 -> bf16 cast (weights) ----------------
__global__ __launch_bounds__(256) void cast_bf16_kernel(const float* __restrict__ in,
                                                        ushort* __restrict__ out){
  int i = (blockIdx.x * 256 + threadIdx.x) * 4;
  float4 v = *(const float4*)(in + i);
  ushort4 o; o.x = f2bf(v.x); o.y = f2bf(v.y); o.z = f2bf(v.z); o.w = f2bf(v.w);
  *(ushort4*)(out + i) = o;
}

// ---------------- LN1 ----------------
__global__ __launch_bounds__(256) void ln1_kernel(const float* __restrict__ x,
    const float* __restrict__ gw, const float* __restrict__ bw,
    ushort* __restrict__ hout){
  int row = blockIdx.x, tid = threadIdx.x;
  size_t base = (size_t)row * Cc + tid * 4;
  float4 xv = *(const float4*)(x + base);
  float s  = xv.x + xv.y + xv.z + xv.w;
  float ss = xv.x*xv.x + xv.y*xv.y + xv.z*xv.z + xv.w*xv.w;
  #pragma unroll
  for (int off = 1; off < 64; off <<= 1){ s += __shfl_xor(s, off); ss += __shfl_xor(ss, off); }
  __shared__ float red[8];
  int wid = tid >> 6, lane = tid & 63;
  if (lane == 0){ red[wid] = s; red[4 + wid] = ss; }
  __syncthreads();
  s  = red[0] + red[1] + red[2] + red[3];
  ss = red[4] + red[5] + red[6] + red[7];
  float mu = s * (1.0f / Cc);
  float rstd = rsqrtf(ss * (1.0f / Cc) - mu * mu + 1e-5f);
  float4 gv = *(const float4*)(gw + tid * 4);
  float4 bv = *(const float4*)(bw + tid * 4);
  ushort4 o;
  o.x = f2bf((xv.x - mu) * rstd * gv.x + bv.x);
  o.y = f2bf((xv.y - mu) * rstd * gv.y + bv.y);
  o.z = f2bf((xv.z - mu) * rstd * gv.z + bv.z);
  o.w = f2bf((xv.w - mu) * rstd * gv.w + bv.w);
  *(ushort4*)(hout + base) = o;
}

// ---------------- LN2: x2 = x + attn -> d_out, h2 = LN(x2) -> bf16 ----------------
__global__ __launch_bounds__(256) void ln2_kernel(const float* __restrict__ x,
    const ushort* __restrict__ attnb,
    const float* __restrict__ gw, const float* __restrict__ bw,
    float* __restrict__ x2, ushort* __restrict__ hout){
  int row = blockIdx.x, tid = threadIdx.x;
  size_t base = (size_t)row * Cc + tid * 4;
  float4 xv = *(const float4*)(x + base);
  ushort4 av = *(const ushort4*)(attnb + base);
  xv.x += bf2f(av.x); xv.y += bf2f(av.y); xv.z += bf2f(av.z); xv.w += bf2f(av.w);
  *(float4*)(x2 + base) = xv;
  float s  = xv.x + xv.y + xv.z + xv.w;
  float ss = xv.x*xv.x + xv.y*xv.y + xv.z*xv.z + xv.w*xv.w;
  #pragma unroll
  for (int off = 1; off < 64; off <<= 1){ s += __shfl_xor(s, off); ss += __shfl_xor(ss, off); }
  __shared__ float red[8];
  int wid = tid >> 6, lane = tid & 63;
  if (lane == 0){ red[wid] = s; red[4 + wid] = ss; }
  __syncthreads();
  s  = red[0] + red[1] + red[2] + red[3];
  ss = red[4] + red[5] + red[6] + red[7];
  float mu = s * (1.0f / Cc);
  float rstd = rsqrtf(ss * (1.0f / Cc) - mu * mu + 1e-5f);
  float4 gv = *(const float4*)(gw + tid * 4);
  float4 bv = *(const float4*)(bw + tid * 4);
  ushort4 o;
  o.x = f2bf((xv.x - mu) * rstd * gv.x + bv.x);
  o.y = f2bf((xv.y - mu) * rstd * gv.y + bv.y);
  o.z = f2bf((xv.z - mu) * rstd * gv.z + bv.z);
  o.w = f2bf((xv.w - mu) * rstd * gv.w + bv.w);
  *(ushort4*)(hout + base) = o;
}

// =====================================================================
// 256x256 8-phase GEMM (T1+T2+T3/T4+T5): C[M,N] = A[M,K] * W[N,K]^T
// 512 thr = 8 waves (2M x 4N), per-wave 128x64 out, BK=64, dbuf LDS 128KB.
// Per K-tile t (buf=t&1), 4 phases:
//  P1: ds A-sub0(8)+B-q0(4); stage Ah0(t+1)->buf^1 | bar | lgkm0 | 16 MFMA | bar
//  P2: ds B-q1(4);           stage Ah1(t+1)->buf^1 | bar | lgkm0 | 16 MFMA | bar
//  P3: ds A-sub1(8);         stage Bh0(t+2)->buf   | bar | lgkm0 | 16 MFMA | bar
//  P4:                       stage Bh1(t+2)->buf; vmcnt(4) | bar | 16 MFMA | bar
// LDS swizzle: colb ^= (row&7)<<4 (linear dest, inverse-swizzled src, swz read).
// MODE 0: QKV scatter (N=3072; q*0.125; v transposed). MODE 1: SiLU+bias bf16.
// =====================================================================
#define MFMA_QUAD(SI, QI, BQ) \
  { \
    _Pragma("unroll") \
    for (int mi = 0; mi < 4; ++mi){ \
      acc[(SI)*4+mi][(QI)*2+0] = __builtin_amdgcn_mfma_f32_16x16x32_bf16(af[mi][0], BQ[0][0], acc[(SI)*4+mi][(QI)*2+0], 0,0,0); \
      acc[(SI)*4+mi][(QI)*2+0] = __builtin_amdgcn_mfma_f32_16x16x32_bf16(af[mi][1], BQ[0][1], acc[(SI)*4+mi][(QI)*2+0], 0,0,0); \
      acc[(SI)*4+mi][(QI)*2+1] = __builtin_amdgcn_mfma_f32_16x16x32_bf16(af[mi][0], BQ[1][0], acc[(SI)*4+mi][(QI)*2+1], 0,0,0); \
      acc[(SI)*4+mi][(QI)*2+1] = __builtin_amdgcn_mfma_f32_16x16x32_bf16(af[mi][1], BQ[1][1], acc[(SI)*4+mi][(QI)*2+1], 0,0,0); \
    } \
  }

#define PH_SYNC_PRE()  { __builtin_amdgcn_sched_barrier(0); __builtin_amdgcn_s_barrier(); \
                         asm volatile("s_waitcnt lgkmcnt(0)" ::: "memory"); \
                         __builtin_amdgcn_sched_barrier(0); __builtin_amdgcn_s_setprio(1); }
#define PH_SYNC_POST() { __builtin_amdgcn_s_setprio(0); __builtin_amdgcn_sched_barrier(0); \
                         __builtin_amdgcn_s_barrier(); }

template<int MODE>
__global__ __launch_bounds__(512, 2) void gemm256_kernel(
    const ushort* __restrict__ A, const ushort* __restrict__ Bw,
    int N, int K,
    ushort* __restrict__ obf, float* __restrict__ of32,
    const float* __restrict__ bias)
{
  __shared__ __align__(16) ushort lds[2][2][2][128 * 64];  // [buf][A/B][half][128r x 64k]
  int tid = threadIdx.x, lane = tid & 63, wid = tid >> 6;
  int wm = wid >> 2, wn = wid & 3;
  int c = lane & 15, g = lane >> 4;

  // XCD-aware bijective block swizzle (grids here are %8 == 0)
  int nwg = gridDim.x, bid = blockIdx.x;
  int wgid = (bid & 7) * (nwg >> 3) + (bid >> 3);
  int nTn = N >> 8;
  int m0 = (wgid / nTn) << 8, n0 = (wgid % nTn) << 8;

  const ushort* Ag = A  + (size_t)m0 * K;
  const ushort* Bg = Bw + (size_t)n0 * K;

  // stage one [128][64] half-tile: 8 waves x 2 gload16. Linear LDS dest,
  // inverse-swizzled global source (involution: colb ^ ((row&7)<<4)).
  auto stage = [&](const ushort* gbase, int t, int ab, int h){
    #pragma unroll
    for (int j = 0; j < 2; ++j){
      int d = j * 8192 + wid * 1024 + lane * 16;
      int row = d >> 7;
      int colb = (d & 127) ^ ((row & 7) << 4);
      gload16((const char*)gbase + ((size_t)(h * 128 + row) * K + t * 64) * 2 + colb,
              (char*)&lds[t & 1][ab][h][0] + j * 8192 + wid * 1024);
    }
  };

  f32x4 acc[8][4] = {};
  bf16x8 af[4][2], bq0[2][2], bq1[2][2];
  int nt = K >> 6;

  // ---- prologue: tile0 fully, tile1's B halves ----
  stage(Ag, 0, 0, 0); stage(Ag, 0, 0, 1);
  stage(Bg, 0, 1, 0); stage(Bg, 0, 1, 1);
  stage(Bg, 1, 1, 0); stage(Bg, 1, 1, 1);
  asm volatile("s_waitcnt vmcnt(4)" ::: "memory");   // tile0's 4 halves landed
  __builtin_amdgcn_sched_barrier(0);
  __builtin_amdgcn_s_barrier();

  for (int t = 0; t < nt; ++t){
    const char* Abuf = (const char*)&lds[t & 1][0][wm][0];
    const char* Bbuf = (const char*)&lds[t & 1][1][wn >> 1][0];
    int brow0 = (wn & 1) * 64;

    // ---- P1 ----
    #pragma unroll
    for (int mi = 0; mi < 4; ++mi){
      int row = mi * 16 + c, sw = (row & 7) << 4;
      af[mi][0] = *(const bf16x8*)(Abuf + row * 128 + ((g * 16) ^ sw));
      af[mi][1] = *(const bf16x8*)(Abuf + row * 128 + ((64 + g * 16) ^ sw));
    }
    #pragma unroll
    for (int nj = 0; nj < 2; ++nj){
      int row = brow0 + nj * 16 + c, sw = (row & 7) << 4;
      bq0[nj][0] = *(const bf16x8*)(Bbuf + row * 128 + ((g * 16) ^ sw));
      bq0[nj][1] = *(const bf16x8*)(Bbuf + row * 128 + ((64 + g * 16) ^ sw));
    }
    if (t + 1 < nt) stage(Ag, t + 1, 0, 0);
    PH_SYNC_PRE();
    MFMA_QUAD(0, 0, bq0);
    PH_SYNC_POST();

    // ---- P2 ----
    #pragma unroll
    for (int nj = 0; nj < 2; ++nj){
      int row = brow0 + 32 + nj * 16 + c, sw = (row & 7) << 4;
      bq1[nj][0] = *(const bf16x8*)(Bbuf + row * 128 + ((g * 16) ^ sw));
      bq1[nj][1] = *(const bf16x8*)(Bbuf + row * 128 + ((64 + g * 16) ^ sw));
    }
    if (t + 1 < nt) stage(Ag, t + 1, 0, 1);
    PH_SYNC_PRE();
    MFMA_QUAD(0, 1, bq1);
    PH_SYNC_POST();

    // ---- P3 ----
    #pragma unroll
    for (int mi = 0; mi < 4; ++mi){
      int row = 64 + mi * 16 + c, sw = (row & 7) << 4;
      af[mi][0] = *(const bf16x8*)(Abuf + row * 128 + ((g * 16) ^ sw));
      af[mi][1] = *(const bf16x8*)(Abuf + row * 128 + ((64 + g * 16) ^ sw));
    }
    if (t + 2 < nt) stage(Bg, t + 2, 1, 0);
    PH_SYNC_PRE();
    MFMA_QUAD(1, 0, bq0);
    PH_SYNC_POST();

    // ---- P4 ----
    if (t + 2 < nt){
      stage(Bg, t + 2, 1, 1);
      asm volatile("s_waitcnt vmcnt(4)" ::: "memory");  // tile t+1 fully landed
    } else {
      asm volatile("s_waitcnt vmcnt(0)" ::: "memory");
    }
    __builtin_amdgcn_sched_barrier(0);
    __builtin_amdgcn_s_barrier();
    __builtin_amdgcn_s_setprio(1);
    MFMA_QUAD(1, 1, bq1);
    PH_SYNC_POST();
  }

  // ---- epilogue ----
  #pragma unroll
  for (int mi = 0; mi < 8; ++mi){
    #pragma unroll
    for (int ni = 0; ni < 4; ++ni){
      #pragma unroll
      for (int r = 0; r < 4; ++r){
        float v = acc[mi][ni][r];
        int m = m0 + wm * 128 + mi * 16 + g * 4 + r;
        int n = n0 + wn * 64 + ni * 16 + c;
        if (MODE == 0){
          int which = n >> 10;
          int nn = n & 1023;
          int b = m >> 11, t = m & (Tt - 1);
          int h = nn >> 6, d = nn & 63;
          float vv = (which == 0) ? v * 0.125f : v;   // fold softmax scale into q
          size_t base = (size_t)which * (size_t)(Bb * Tt * Cc);
          size_t idx = (which == 2)
              ? ((((size_t)(b * Hh + h)) * HSs + d) * Tt + t)     // V^T [B,H,HS,T]
              : ((((size_t)(b * Hh + h)) * Tt + t) * HSs + d);    // Q,K [B,H,T,HS]
          obf[base + idx] = f2bf(vv);
        } else {
          v += bias[n];
          float sv = v / (1.0f + __expf(-v));   // SiLU
          obf[(size_t)m * N + n] = f2bf(sv);
        }
      }
    }
  }
}

// ---------------- 128x128 GEMM (kept for FFN2): of32[idx] += acc + bias ----------------
__global__ __launch_bounds__(256) void gemm_bt2_kernel(
    const ushort* __restrict__ A, const ushort* __restrict__ Bw,
    int N, int K, float* __restrict__ of32, const float* __restrict__ bias)
{
  __shared__ __align__(16) ushort Asm[128 * 64];
  __shared__ __align__(16) ushort Bsm[128 * 64];
  int tid = threadIdx.x;
  int lane = tid & 63, wid = tid >> 6;
  int wm = wid >> 1, wn = wid & 1;
  int m0 = blockIdx.y * 128, n0 = blockIdx.x * 128;
  int srow = lane >> 3, schunk = lane & 7;
  int c = lane & 15, g = lane >> 4;
  f32x4 acc[4][4] = {};

  for (int k0 = 0; k0 < K; k0 += 64){
    #pragma unroll
    for (int it = 0; it < 4; ++it){
      int row = wid * 32 + it * 8 + srow;
      gload16(A  + (size_t)(m0 + row) * K + k0 + schunk * 8,
              Asm + (size_t)(wid * 32 + it * 8) * 64);
      gload16(Bw + (size_t)(n0 + row) * K + k0 + schunk * 8,
              Bsm + (size_t)(wid * 32 + it * 8) * 64);
    }
    __syncthreads();
    #pragma unroll
    for (int ks = 0; ks < 2; ++ks){
      bf16x8 af[4], bfr[4];
      #pragma unroll
      for (int mi = 0; mi < 4; ++mi)
        af[mi] = *(const bf16x8*)(Asm + (wm * 64 + mi * 16 + c) * 64 + ks * 32 + g * 8);
      #pragma unroll
      for (int ni = 0; ni < 4; ++ni)
        bfr[ni] = *(const bf16x8*)(Bsm + (wn * 64 + ni * 16 + c) * 64 + ks * 32 + g * 8);
      #pragma unroll
      for (int mi = 0; mi < 4; ++mi)
        #pragma unroll
        for (int ni = 0; ni < 4; ++ni)
          acc[mi][ni] = __builtin_amdgcn_mfma_f32_16x16x32_bf16(af[mi], bfr[ni], acc[mi][ni], 0, 0, 0);
    }
    __syncthreads();
  }

  #pragma unroll
  for (int mi = 0; mi < 4; ++mi)
    #pragma unroll
    for (int ni = 0; ni < 4; ++ni)
      #pragma unroll
      for (int r = 0; r < 4; ++r){
        int m = m0 + wm * 64 + mi * 16 + g * 4 + r;
        int n = n0 + wn * 64 + ni * 16 + c;
        size_t idx = (size_t)m * Cc + n;
        of32[idx] = of32[idx] + acc[mi][ni][r] + bias[n];
      }
}

// ---------------- causal flash attention (unchanged from R3) ----------------
__global__ __launch_bounds__(256, 3) void attn_kernel(
    const ushort* __restrict__ q, const ushort* __restrict__ k,
    const ushort* __restrict__ vt, ushort* __restrict__ attnb)
{
  __shared__ __align__(16) ushort Ksm[2][64 * 64];
  __shared__ __align__(16) ushort Vsm[2][64 * 64];
  __shared__ __align__(16) ushort Pl[4][32 * 64];

  int bh  = blockIdx.y;
  int qb  = gridDim.x - 1 - blockIdx.x;
  int tid = threadIdx.x, wid = tid >> 6, lane = tid & 63;
  int g = lane >> 4, c = lane & 15;
  int q0 = qb * 128 + wid * 32;
  const ushort* Qb = q  + (size_t)bh * Tt * HSs;
  const ushort* Kb = k  + (size_t)bh * Tt * HSs;
  const ushort* Vt = vt + (size_t)bh * HSs * Tt;
  char* Pw = (char*)&Pl[wid][0];

  auto stageKV = [&](int bsel, int s0){
    #pragma unroll
    for (int half = 0; half < 2; ++half){
      int i = wid + half * 4;
      int row = i * 8 + (lane >> 3);
      int col = ((lane & 7) ^ (row & 7)) * 8;
      gload16(Kb + (size_t)(s0 + row) * HSs + col, &Ksm[bsel][i * 512]);
      gload16(Vt + (size_t)row * Tt + s0 + col,    &Vsm[bsel][i * 512]);
    }
  };

  bf16x8 qf[2][2];
  #pragma unroll
  for (int mi = 0; mi < 2; ++mi)
    #pragma unroll
    for (int ks = 0; ks < 2; ++ks)
      qf[mi][ks] = *(const bf16x8*)(Qb + (size_t)(q0 + mi * 16 + c) * HSs + ks * 32 + g * 8);

  f32x4 o[2][4] = {};
  float mrow[2][4], lpart[2][4];
  #pragma unroll
  for (int mi = 0; mi < 2; ++mi)
    #pragma unroll
    for (int r = 0; r < 4; ++r){ mrow[mi][r] = -1e30f; lpart[mi][r] = 0.f; }

  int nch    = qb * 2 + 2;
  int ccount = qb * 2 + 1 + (wid >> 1);

  stageKV(0, 0);
  asm volatile("s_waitcnt vmcnt(0)" ::: "memory");
  __builtin_amdgcn_s_barrier();

  for (int ch = 0; ch < nch; ++ch){
    int buf = ch & 1;
    if (ch + 1 < nch) stageKV(buf ^ 1, (ch + 1) * 64);

    if (ch < ccount){
      int s0 = ch * 64;
      const char* Kbuf = (const char*)&Ksm[buf][0];
      const char* Vbuf = (const char*)&Vsm[buf][0];

      f32x4 S[2][4] = {};
      bf16x8 kf[4][2];
      #pragma unroll
      for (int ni = 0; ni < 4; ++ni)
        #pragma unroll
        for (int ks = 0; ks < 2; ++ks)
          kf[ni][ks] = *(const bf16x8*)(Kbuf + (ni * 16 + c) * 128 + (((ks * 4 + g) ^ (c & 7)) << 4));
      #pragma unroll
      for (int mi = 0; mi < 2; ++mi)
        #pragma unroll
        for (int ni = 0; ni < 4; ++ni)
          #pragma unroll
          for (int ks = 0; ks < 2; ++ks)
            S[mi][ni] = __builtin_amdgcn_mfma_f32_16x16x32_bf16(qf[mi][ks], kf[ni][ks], S[mi][ni], 0, 0, 0);

      if (s0 + 63 > q0){
        #pragma unroll
        for (int mi = 0; mi < 2; ++mi)
          #pragma unroll
          for (int ni = 0; ni < 4; ++ni)
            #pragma unroll
            for (int r = 0; r < 4; ++r){
              int tl = q0 + mi * 16 + g * 4 + r, sl = s0 + ni * 16 + c;
              if (sl > tl) S[mi][ni][r] = -1e30f;
            }
      }

      float lmax[2][4], worst = -1e30f;
      #pragma unroll
      for (int mi = 0; mi < 2; ++mi)
        #pragma unroll
        for (int r = 0; r < 4; ++r){
          float a0 = fmaxf(S[mi][0][r], S[mi][1][r]);
          float a1 = fmaxf(S[mi][2][r], S[mi][3][r]);
          lmax[mi][r] = fmaxf(a0, a1);
          worst = fmaxf(worst, lmax[mi][r] - mrow[mi][r]);
        }
      if (!__all(worst <= 8.0f)){
        #pragma unroll
        for (int mi = 0; mi < 2; ++mi)
          #pragma unroll
          for (int r = 0; r < 4; ++r){
            float mx = lmax[mi][r];
            mx = fmaxf(mx, __shfl_xor(mx, 1));
            mx = fmaxf(mx, __shfl_xor(mx, 2));
            mx = fmaxf(mx, __shfl_xor(mx, 4));
            mx = fmaxf(mx, __shfl_xor(mx, 8));
            float mnew  = fmaxf(mrow[mi][r], mx);
            float alpha = __expf(mrow[mi][r] - mnew);
            lpart[mi][r] *= alpha;
            #pragma unroll
            for (int dt = 0; dt < 4; ++dt) o[mi][dt][r] *= alpha;
            mrow[mi][r] = mnew;
          }
      }
      #pragma unroll
      for (int mi = 0; mi < 2; ++mi)
        #pragma unroll
        for (int r = 0; r < 4; ++r){
          int row = mi * 16 + g * 4 + r;
          float mb = mrow[mi][r] * 1.44269504f;
          float p[4];
          #pragma unroll
          for (int ni = 0; ni < 4; ++ni){
            p[ni] = exp2f(__builtin_fmaf(S[mi][ni][r], 1.44269504f, -mb));
            *(ushort*)(Pw + row * 128 + (((ni * 32 + 2 * c) ^ ((row & 7) << 4)))) = f2bf(p[ni]);
          }
          lpart[mi][r] += (p[0] + p[1]) + (p[2] + p[3]);
        }
      __builtin_amdgcn_sched_barrier(0);

      bf16x8 vf[4][2];
      #pragma unroll
      for (int dt = 0; dt < 4; ++dt)
        #pragma unroll
        for (int ks = 0; ks < 2; ++ks)
          vf[dt][ks] = *(const bf16x8*)(Vbuf + (dt * 16 + c) * 128 + (((ks * 4 + g) ^ (c & 7)) << 4));
      #pragma unroll
      for (int mi = 0; mi < 2; ++mi){
        #pragma unroll
        for (int ks = 0; ks < 2; ++ks){
          bf16x8 pf = *(const bf16x8*)(Pw + (mi * 16 + c) * 128 + ((((ks * 4 + g) ^ (c & 7)) << 4)));
          #pragma unroll
          for (int dt = 0; dt < 4; ++dt)
            o[mi][dt] = __builtin_amdgcn_mfma_f32_16x16x32_bf16(pf, vf[dt][ks], o[mi][dt], 0, 0, 0);
        }
      }
      __builtin_amdgcn_sched_barrier(0);
    }

    asm volatile("s_waitcnt vmcnt(0) lgkmcnt(0)" ::: "memory");
    __builtin_amdgcn_s_barrier();
  }

  float linv[2][4];
  #pragma unroll
  for (int mi = 0; mi < 2; ++mi)
    #pragma unroll
    for (int r = 0; r < 4; ++r){
      float ls = lpart[mi][r];
      ls += __shfl_xor(ls, 1);
      ls += __shfl_xor(ls, 2);
      ls += __shfl_xor(ls, 4);
      ls += __shfl_xor(ls, 8);
      linv[mi][r] = 1.0f / ls;
    }
  int b = bh >> 4, h = bh & 15;
  #pragma unroll
  for (int mi = 0; mi < 2; ++mi)
    #pragma unroll
    for (int dt = 0; dt < 4; ++dt)
      #pragma unroll
      for (int r = 0; r < 4; ++r){
        int t = q0 + mi * 16 + g * 4 + r;
        attnb[((size_t)(b * Tt + t)) * Cc + h * HSs + dt * 16 + c] = f2bf(o[mi][dt][r] * linv[mi][r]);
      }
}

extern "C" void kernel_launch(void* const* d_in, const int* in_sizes, int n_in,
                              void* d_out, int out_size, void* d_ws, size_t ws_size,
                              hipStream_t stream) {
  (void)in_sizes; (void)n_in; (void)out_size; (void)ws_size;
  const float* x    = (const float*)d_in[0];
  const float* wq   = (const float*)d_in[2];
  const float* wk   = (const float*)d_in[3];
  const float* wv   = (const float*)d_in[4];
  const float* ln1g = (const float*)d_in[5];
  const float* ln1b = (const float*)d_in[6];
  const float* ln2g = (const float*)d_in[7];
  const float* ln2b = (const float*)d_in[8];
  const float* w1   = (const float*)d_in[9];
  const float* b1   = (const float*)d_in[10];
  const float* w2   = (const float*)d_in[11];
  const float* b2   = (const float*)d_in[12];
  float* out = (float*)d_out;

  char* ws = (char*)d_ws;
  const size_t SZ_ACT = (size_t)Bb * Tt * Cc * 2;
  ushort* h1    = (ushort*)(ws);
  ushort* qbuf  = (ushort*)(ws + SZ_ACT);
  ushort* kbuf  = (ushort*)(ws + 2 * SZ_ACT);
  ushort* vbuf  = (ushort*)(ws + 3 * SZ_ACT);   // V^T [B,H,HS,T]
  ushort* attnb = (ushort*)(ws + 4 * SZ_ACT);
  ushort* h2    = (ushort*)(ws + 5 * SZ_ACT);
  ushort* h3    = (ushort*)(ws + 6 * SZ_ACT);
  char*   wsw   = ws + 6 * SZ_ACT + (size_t)Bb * Tt * 4 * Cc * 2;
  ushort* wqb = (ushort*)(wsw);                 // wq,wk,wv contiguous -> [3072,1024]
  ushort* wkb = (ushort*)(wsw + (size_t)Cc * Cc * 2);
  ushort* wvb = (ushort*)(wsw + 2 * (size_t)Cc * Cc * 2);
  ushort* w1b = (ushort*)(wsw + 3 * (size_t)Cc * Cc * 2);
  ushort* w2b = (ushort*)(wsw + 3 * (size_t)Cc * Cc * 2 + (size_t)4 * Cc * Cc * 2);

  cast_bf16_kernel<<<dim3(Cc * Cc / 1024), 256, 0, stream>>>(wq, wqb);
  cast_bf16_kernel<<<dim3(Cc * Cc / 1024), 256, 0, stream>>>(wk, wkb);
  cast_bf16_kernel<<<dim3(Cc * Cc / 1024), 256, 0, stream>>>(wv, wvb);
  cast_bf16_kernel<<<dim3(4 * Cc * Cc / 1024), 256, 0, stream>>>(w1, w1b);
  cast_bf16_kernel<<<dim3(4 * Cc * Cc / 1024), 256, 0, stream>>>(w2, w2b);

  ln1_kernel<<<dim3(Bb * Tt), 256, 0, stream>>>(x, ln1g, ln1b, h1);

  // fused QKV projection: [8192,3072] = h1 @ [3072,1024]^T, 256^2 8-phase
  gemm256_kernel<0><<<dim3(32 * 12), 512, 0, stream>>>(h1, wqb, 3 * Cc, Cc, qbuf, nullptr, nullptr);

  attn_kernel<<<dim3(Tt / 128, Bb * Hh), 256, 0, stream>>>(qbuf, kbuf, vbuf, attnb);

  ln2_kernel<<<dim3(Bb * Tt), 256, 0, stream>>>(x, attnb, ln2g, ln2b, out, h2);

  // FFN1: [8192,4096] = h2 @ w1^T, 256^2 8-phase, SiLU epilogue
  gemm256_kernel<1><<<dim3(32 * 16), 512, 0, stream>>>(h2, w1b, 4 * Cc, Cc, h3, nullptr, b1);
  // FFN2: 128^2 kernel, residual epilogue
  gemm_bt2_kernel<<<dim3(8, 64), 256, 0, stream>>>(h3, w2b, Cc, 4 * Cc, out, b2);
}

// Round 5
// 405.969 us; speedup vs baseline: 1.7152x; 1.2169x over previous
//
#include <hip/hip_runtime.h>
#include <stdint.h>

#define Bb 4
#define Tt 2048
#define Cc 1024
#define Hh 16
#define HSs 64

typedef __attribute__((ext_vector_type(8))) __bf16 bf16x8;
typedef __attribute__((ext_vector_type(4))) float f32x4;

__device__ __forceinline__ ushort f2bf(float f){
  union { float f; uint u; } c; c.f = f;
  uint r = c.u + 0x7fffu + ((c.u >> 16) & 1u);
  return (ushort)(r >> 16);
}
__device__ __forceinline__ float bf2f(ushort u){
  union { uint u; float f; } c; c.u = ((uint)u) << 16; return c.f;
}

// async global->LDS, 16B per lane. LDS dest wave-uniform base; HW adds lane*16.
__device__ __forceinline__ void gload16(const void* g, void* l){
  __builtin_amdgcn_global_load_lds(
      (__attribute__((address_space(1))) void*)(g),
      (__attribute__((address_space(3))) void*)(l), 16, 0, 0);
}

// ---------------- elementwise fp32 -> bf16 cast (weights) ----------------
__global__ __launch_bounds__(256) void cast_bf16_kernel(const float* __restrict__ in,
                                                        ushort* __restrict__ out){
  int i = (blockIdx.x * 256 + threadIdx.x) * 4;
  float4 v = *(const float4*)(in + i);
  ushort4 o; o.x = f2bf(v.x); o.y = f2bf(v.y); o.z = f2bf(v.z); o.w = f2bf(v.w);
  *(ushort4*)(out + i) = o;
}

// ---------------- LN1 ----------------
__global__ __launch_bounds__(256) void ln1_kernel(const float* __restrict__ x,
    const float* __restrict__ gw, const float* __restrict__ bw,
    ushort* __restrict__ hout){
  int row = blockIdx.x, tid = threadIdx.x;
  size_t base = (size_t)row * Cc + tid * 4;
  float4 xv = *(const float4*)(x + base);
  float s  = xv.x + xv.y + xv.z + xv.w;
  float ss = xv.x*xv.x + xv.y*xv.y + xv.z*xv.z + xv.w*xv.w;
  #pragma unroll
  for (int off = 1; off < 64; off <<= 1){ s += __shfl_xor(s, off); ss += __shfl_xor(ss, off); }
  __shared__ float red[8];
  int wid = tid >> 6, lane = tid & 63;
  if (lane == 0){ red[wid] = s; red[4 + wid] = ss; }
  __syncthreads();
  s  = red[0] + red[1] + red[2] + red[3];
  ss = red[4] + red[5] + red[6] + red[7];
  float mu = s * (1.0f / Cc);
  float rstd = rsqrtf(ss * (1.0f / Cc) - mu * mu + 1e-5f);
  float4 gv = *(const float4*)(gw + tid * 4);
  float4 bv = *(const float4*)(bw + tid * 4);
  ushort4 o;
  o.x = f2bf((xv.x - mu) * rstd * gv.x + bv.x);
  o.y = f2bf((xv.y - mu) * rstd * gv.y + bv.y);
  o.z = f2bf((xv.z - mu) * rstd * gv.z + bv.z);
  o.w = f2bf((xv.w - mu) * rstd * gv.w + bv.w);
  *(ushort4*)(hout + base) = o;
}

// ---------------- LN2: x2 = x + attn -> d_out, h2 = LN(x2) -> bf16 ----------------
__global__ __launch_bounds__(256) void ln2_kernel(const float* __restrict__ x,
    const ushort* __restrict__ attnb,
    const float* __restrict__ gw, const float* __restrict__ bw,
    float* __restrict__ x2, ushort* __restrict__ hout){
  int row = blockIdx.x, tid = threadIdx.x;
  size_t base = (size_t)row * Cc + tid * 4;
  float4 xv = *(const float4*)(x + base);
  ushort4 av = *(const ushort4*)(attnb + base);
  xv.x += bf2f(av.x); xv.y += bf2f(av.y); xv.z += bf2f(av.z); xv.w += bf2f(av.w);
  *(float4*)(x2 + base) = xv;
  float s  = xv.x + xv.y + xv.z + xv.w;
  float ss = xv.x*xv.x + xv.y*xv.y + xv.z*xv.z + xv.w*xv.w;
  #pragma unroll
  for (int off = 1; off < 64; off <<= 1){ s += __shfl_xor(s, off); ss += __shfl_xor(ss, off); }
  __shared__ float red[8];
  int wid = tid >> 6, lane = tid & 63;
  if (lane == 0){ red[wid] = s; red[4 + wid] = ss; }
  __syncthreads();
  s  = red[0] + red[1] + red[2] + red[3];
  ss = red[4] + red[5] + red[6] + red[7];
  float mu = s * (1.0f / Cc);
  float rstd = rsqrtf(ss * (1.0f / Cc) - mu * mu + 1e-5f);
  float4 gv = *(const float4*)(gw + tid * 4);
  float4 bv = *(const float4*)(bw + tid * 4);
  ushort4 o;
  o.x = f2bf((xv.x - mu) * rstd * gv.x + bv.x);
  o.y = f2bf((xv.y - mu) * rstd * gv.y + bv.y);
  o.z = f2bf((xv.z - mu) * rstd * gv.z + bv.z);
  o.w = f2bf((xv.w - mu) * rstd * gv.w + bv.w);
  *(ushort4*)(hout + base) = o;
}

// =====================================================================
// 256x256 8-phase GEMM (unchanged from R4)
// =====================================================================
#define MFMA_QUAD(SI, QI, BQ) \
  { \
    _Pragma("unroll") \
    for (int mi = 0; mi < 4; ++mi){ \
      acc[(SI)*4+mi][(QI)*2+0] = __builtin_amdgcn_mfma_f32_16x16x32_bf16(af[mi][0], BQ[0][0], acc[(SI)*4+mi][(QI)*2+0], 0,0,0); \
      acc[(SI)*4+mi][(QI)*2+0] = __builtin_amdgcn_mfma_f32_16x16x32_bf16(af[mi][1], BQ[0][1], acc[(SI)*4+mi][(QI)*2+0], 0,0,0); \
      acc[(SI)*4+mi][(QI)*2+1] = __builtin_amdgcn_mfma_f32_16x16x32_bf16(af[mi][0], BQ[1][0], acc[(SI)*4+mi][(QI)*2+1], 0,0,0); \
      acc[(SI)*4+mi][(QI)*2+1] = __builtin_amdgcn_mfma_f32_16x16x32_bf16(af[mi][1], BQ[1][1], acc[(SI)*4+mi][(QI)*2+1], 0,0,0); \
    } \
  }

#define PH_SYNC_PRE()  { __builtin_amdgcn_sched_barrier(0); __builtin_amdgcn_s_barrier(); \
                         asm volatile("s_waitcnt lgkmcnt(0)" ::: "memory"); \
                         __builtin_amdgcn_sched_barrier(0); __builtin_amdgcn_s_setprio(1); }
#define PH_SYNC_POST() { __builtin_amdgcn_s_setprio(0); __builtin_amdgcn_sched_barrier(0); \
                         __builtin_amdgcn_s_barrier(); }

template<int MODE>
__global__ __launch_bounds__(512, 2) void gemm256_kernel(
    const ushort* __restrict__ A, const ushort* __restrict__ Bw,
    int N, int K,
    ushort* __restrict__ obf, float* __restrict__ of32,
    const float* __restrict__ bias)
{
  __shared__ __align__(16) ushort lds[2][2][2][128 * 64];  // [buf][A/B][half][128r x 64k]
  int tid = threadIdx.x, lane = tid & 63, wid = tid >> 6;
  int wm = wid >> 2, wn = wid & 3;
  int c = lane & 15, g = lane >> 4;

  int nwg = gridDim.x, bid = blockIdx.x;
  int wgid = (bid & 7) * (nwg >> 3) + (bid >> 3);
  int nTn = N >> 8;
  int m0 = (wgid / nTn) << 8, n0 = (wgid % nTn) << 8;

  const ushort* Ag = A  + (size_t)m0 * K;
  const ushort* Bg = Bw + (size_t)n0 * K;

  auto stage = [&](const ushort* gbase, int t, int ab, int h){
    #pragma unroll
    for (int j = 0; j < 2; ++j){
      int d = j * 8192 + wid * 1024 + lane * 16;
      int row = d >> 7;
      int colb = (d & 127) ^ ((row & 7) << 4);
      gload16((const char*)gbase + ((size_t)(h * 128 + row) * K + t * 64) * 2 + colb,
              (char*)&lds[t & 1][ab][h][0] + j * 8192 + wid * 1024);
    }
  };

  f32x4 acc[8][4] = {};
  bf16x8 af[4][2], bq0[2][2], bq1[2][2];
  int nt = K >> 6;

  stage(Ag, 0, 0, 0); stage(Ag, 0, 0, 1);
  stage(Bg, 0, 1, 0); stage(Bg, 0, 1, 1);
  stage(Bg, 1, 1, 0); stage(Bg, 1, 1, 1);
  asm volatile("s_waitcnt vmcnt(4)" ::: "memory");
  __builtin_amdgcn_sched_barrier(0);
  __builtin_amdgcn_s_barrier();

  for (int t = 0; t < nt; ++t){
    const char* Abuf = (const char*)&lds[t & 1][0][wm][0];
    const char* Bbuf = (const char*)&lds[t & 1][1][wn >> 1][0];
    int brow0 = (wn & 1) * 64;

    // ---- P1 ----
    #pragma unroll
    for (int mi = 0; mi < 4; ++mi){
      int row = mi * 16 + c, sw = (row & 7) << 4;
      af[mi][0] = *(const bf16x8*)(Abuf + row * 128 + ((g * 16) ^ sw));
      af[mi][1] = *(const bf16x8*)(Abuf + row * 128 + ((64 + g * 16) ^ sw));
    }
    #pragma unroll
    for (int nj = 0; nj < 2; ++nj){
      int row = brow0 + nj * 16 + c, sw = (row & 7) << 4;
      bq0[nj][0] = *(const bf16x8*)(Bbuf + row * 128 + ((g * 16) ^ sw));
      bq0[nj][1] = *(const bf16x8*)(Bbuf + row * 128 + ((64 + g * 16) ^ sw));
    }
    if (t + 1 < nt) stage(Ag, t + 1, 0, 0);
    PH_SYNC_PRE();
    MFMA_QUAD(0, 0, bq0);
    PH_SYNC_POST();

    // ---- P2 ----
    #pragma unroll
    for (int nj = 0; nj < 2; ++nj){
      int row = brow0 + 32 + nj * 16 + c, sw = (row & 7) << 4;
      bq1[nj][0] = *(const bf16x8*)(Bbuf + row * 128 + ((g * 16) ^ sw));
      bq1[nj][1] = *(const bf16x8*)(Bbuf + row * 128 + ((64 + g * 16) ^ sw));
    }
    if (t + 1 < nt) stage(Ag, t + 1, 0, 1);
    PH_SYNC_PRE();
    MFMA_QUAD(0, 1, bq1);
    PH_SYNC_POST();

    // ---- P3 ----
    #pragma unroll
    for (int mi = 0; mi < 4; ++mi){
      int row = 64 + mi * 16 + c, sw = (row & 7) << 4;
      af[mi][0] = *(const bf16x8*)(Abuf + row * 128 + ((g * 16) ^ sw));
      af[mi][1] = *(const bf16x8*)(Abuf + row * 128 + ((64 + g * 16) ^ sw));
    }
    if (t + 2 < nt) stage(Bg, t + 2, 1, 0);
    PH_SYNC_PRE();
    MFMA_QUAD(1, 0, bq0);
    PH_SYNC_POST();

    // ---- P4 ----
    if (t + 2 < nt){
      stage(Bg, t + 2, 1, 1);
      asm volatile("s_waitcnt vmcnt(4)" ::: "memory");
    } else {
      asm volatile("s_waitcnt vmcnt(0)" ::: "memory");
    }
    __builtin_amdgcn_sched_barrier(0);
    __builtin_amdgcn_s_barrier();
    __builtin_amdgcn_s_setprio(1);
    MFMA_QUAD(1, 1, bq1);
    PH_SYNC_POST();
  }

  #pragma unroll
  for (int mi = 0; mi < 8; ++mi){
    #pragma unroll
    for (int ni = 0; ni < 4; ++ni){
      #pragma unroll
      for (int r = 0; r < 4; ++r){
        float v = acc[mi][ni][r];
        int m = m0 + wm * 128 + mi * 16 + g * 4 + r;
        int n = n0 + wn * 64 + ni * 16 + c;
        if (MODE == 0){
          int which = n >> 10;
          int nn = n & 1023;
          int b = m >> 11, t = m & (Tt - 1);
          int h = nn >> 6, d = nn & 63;
          float vv = (which == 0) ? v * 0.125f : v;
          size_t base = (size_t)which * (size_t)(Bb * Tt * Cc);
          size_t idx = (which == 2)
              ? ((((size_t)(b * Hh + h)) * HSs + d) * Tt + t)     // V^T [B,H,HS,T]
              : ((((size_t)(b * Hh + h)) * Tt + t) * HSs + d);    // Q,K [B,H,T,HS]
          obf[base + idx] = f2bf(vv);
        } else {
          v += bias[n];
          float sv = v / (1.0f + __expf(-v));   // SiLU
          obf[(size_t)m * N + n] = f2bf(sv);
        }
      }
    }
  }
}

// ---------------- 128x128 GEMM (FFN2): of32[idx] += acc + bias ----------------
__global__ __launch_bounds__(256) void gemm_bt2_kernel(
    const ushort* __restrict__ A, const ushort* __restrict__ Bw,
    int N, int K, float* __restrict__ of32, const float* __restrict__ bias)
{
  __shared__ __align__(16) ushort Asm[128 * 64];
  __shared__ __align__(16) ushort Bsm[128 * 64];
  int tid = threadIdx.x;
  int lane = tid & 63, wid = tid >> 6;
  int wm = wid >> 1, wn = wid & 1;
  int m0 = blockIdx.y * 128, n0 = blockIdx.x * 128;
  int srow = lane >> 3, schunk = lane & 7;
  int c = lane & 15, g = lane >> 4;
  f32x4 acc[4][4] = {};

  for (int k0 = 0; k0 < K; k0 += 64){
    #pragma unroll
    for (int it = 0; it < 4; ++it){
      int row = wid * 32 + it * 8 + srow;
      gload16(A  + (size_t)(m0 + row) * K + k0 + schunk * 8,
              Asm + (size_t)(wid * 32 + it * 8) * 64);
      gload16(Bw + (size_t)(n0 + row) * K + k0 + schunk * 8,
              Bsm + (size_t)(wid * 32 + it * 8) * 64);
    }
    __syncthreads();
    #pragma unroll
    for (int ks = 0; ks < 2; ++ks){
      bf16x8 af[4], bfr[4];
      #pragma unroll
      for (int mi = 0; mi < 4; ++mi)
        af[mi] = *(const bf16x8*)(Asm + (wm * 64 + mi * 16 + c) * 64 + ks * 32 + g * 8);
      #pragma unroll
      for (int ni = 0; ni < 4; ++ni)
        bfr[ni] = *(const bf16x8*)(Bsm + (wn * 64 + ni * 16 + c) * 64 + ks * 32 + g * 8);
      #pragma unroll
      for (int mi = 0; mi < 4; ++mi)
        #pragma unroll
        for (int ni = 0; ni < 4; ++ni)
          acc[mi][ni] = __builtin_amdgcn_mfma_f32_16x16x32_bf16(af[mi], bfr[ni], acc[mi][ni], 0, 0, 0);
    }
    __syncthreads();
  }

  #pragma unroll
  for (int mi = 0; mi < 4; ++mi)
    #pragma unroll
    for (int ni = 0; ni < 4; ++ni)
      #pragma unroll
      for (int r = 0; r < 4; ++r){
        int m = m0 + wm * 64 + mi * 16 + g * 4 + r;
        int n = n0 + wn * 64 + ni * 16 + c;
        size_t idx = (size_t)m * Cc + n;
        of32[idx] = of32[idx] + acc[mi][ni][r] + bias[n];
      }
}

// ---------------- causal flash attention, R5 ----------------
// Block p (0..7) processes q-tile PAIR {15-p, p} jointly on ONE shared KV
// stream (tile-lo's KV range is a prefix of tile-hi's): exactly 34
// chunk-computes per block -> perfect balance, 512 blocks = 2/CU all resident.
// Ring-3 KV LDS buffers + counted vmcnt(4): prefetch stays in flight across
// barriers (T4). 4 waves x 32 q-rows per tile. Defer-max softmax (T13).
__global__ __launch_bounds__(256, 2) void attn_kernel(
    const ushort* __restrict__ q, const ushort* __restrict__ k,
    const ushort* __restrict__ vt, ushort* __restrict__ attnb)
{
  __shared__ __align__(16) ushort Ksm[3][64 * 64];
  __shared__ __align__(16) ushort Vsm[3][64 * 64];
  __shared__ __align__(16) ushort Pl[4][32 * 64];

  int bh  = blockIdx.y;
  int p   = blockIdx.x;                       // 0..7
  int tid = threadIdx.x, wid = tid >> 6, lane = tid & 63;
  int g = lane >> 4, c = lane & 15;
  int qbA = 15 - p, qbB = p;                  // A = long tile, B = short tile
  int q0A = qbA * 128 + wid * 32;
  int q0B = qbB * 128 + wid * 32;
  const ushort* Qb = q  + (size_t)bh * Tt * HSs;
  const ushort* Kb = k  + (size_t)bh * Tt * HSs;
  const ushort* Vt = vt + (size_t)bh * HSs * Tt;
  char* Pw = (char*)&Pl[wid][0];

  auto stageKV = [&](int bsel, int s0){
    #pragma unroll
    for (int half = 0; half < 2; ++half){
      int i = wid + half * 4;                 // 0..7
      int row = i * 8 + (lane >> 3);          // 0..63
      int col = ((lane & 7) ^ (row & 7)) * 8; // inverse-swizzled source
      gload16(Kb + (size_t)(s0 + row) * HSs + col, &Ksm[bsel][i * 512]);
      gload16(Vt + (size_t)row * Tt + s0 + col,    &Vsm[bsel][i * 512]);
    }
  };

  // Q fragments for both tiles (issued before stages; drained by first vmcnt)
  bf16x8 qfA[2][2], qfB[2][2];
  #pragma unroll
  for (int mi = 0; mi < 2; ++mi)
    #pragma unroll
    for (int ks = 0; ks < 2; ++ks){
      qfA[mi][ks] = *(const bf16x8*)(Qb + (size_t)(q0A + mi * 16 + c) * HSs + ks * 32 + g * 8);
      qfB[mi][ks] = *(const bf16x8*)(Qb + (size_t)(q0B + mi * 16 + c) * HSs + ks * 32 + g * 8);
    }

  f32x4 oA[2][4] = {}, oB[2][4] = {};
  float mA[2][4], lA[2][4], mB[2][4], lB[2][4];
  #pragma unroll
  for (int mi = 0; mi < 2; ++mi)
    #pragma unroll
    for (int r = 0; r < 4; ++r){
      mA[mi][r] = -1e30f; lA[mi][r] = 0.f;
      mB[mi][r] = -1e30f; lB[mi][r] = 0.f;
    }

  // one tile-chunk compute: QK^T -> defer-max softmax -> P(LDS) -> PV
  auto computeTile = [&](bf16x8 (&qf)[2][2], f32x4 (&o)[2][4],
                         float (&mrow)[2][4], float (&lpart)[2][4],
                         int q0w, int s0, const char* Kbuf, const char* Vbuf){
    f32x4 S[2][4] = {};
    bf16x8 kf[4][2];
    #pragma unroll
    for (int ni = 0; ni < 4; ++ni)
      #pragma unroll
      for (int ks = 0; ks < 2; ++ks)
        kf[ni][ks] = *(const bf16x8*)(Kbuf + (ni * 16 + c) * 128 + (((ks * 4 + g) ^ (c & 7)) << 4));
    #pragma unroll
    for (int mi = 0; mi < 2; ++mi)
      #pragma unroll
      for (int ni = 0; ni < 4; ++ni)
        #pragma unroll
        for (int ks = 0; ks < 2; ++ks)
          S[mi][ni] = __builtin_amdgcn_mfma_f32_16x16x32_bf16(qf[mi][ks], kf[ni][ks], S[mi][ni], 0, 0, 0);

    if (s0 + 63 > q0w){   // diagonal chunk for this wave
      #pragma unroll
      for (int mi = 0; mi < 2; ++mi)
        #pragma unroll
        for (int ni = 0; ni < 4; ++ni)
          #pragma unroll
          for (int r = 0; r < 4; ++r){
            int tl = q0w + mi * 16 + g * 4 + r, sl = s0 + ni * 16 + c;
            if (sl > tl) S[mi][ni][r] = -1e30f;
          }
    }

    float lmax[2][4], worst = -1e30f;
    #pragma unroll
    for (int mi = 0; mi < 2; ++mi)
      #pragma unroll
      for (int r = 0; r < 4; ++r){
        float a0 = fmaxf(S[mi][0][r], S[mi][1][r]);
        float a1 = fmaxf(S[mi][2][r], S[mi][3][r]);
        lmax[mi][r] = fmaxf(a0, a1);
        worst = fmaxf(worst, lmax[mi][r] - mrow[mi][r]);
      }
    if (!__all(worst <= 8.0f)){
      #pragma unroll
      for (int mi = 0; mi < 2; ++mi)
        #pragma unroll
        for (int r = 0; r < 4; ++r){
          float mx = lmax[mi][r];
          mx = fmaxf(mx, __shfl_xor(mx, 1));
          mx = fmaxf(mx, __shfl_xor(mx, 2));
          mx = fmaxf(mx, __shfl_xor(mx, 4));
          mx = fmaxf(mx, __shfl_xor(mx, 8));
          float mnew  = fmaxf(mrow[mi][r], mx);
          float alpha = __expf(mrow[mi][r] - mnew);
          lpart[mi][r] *= alpha;
          #pragma unroll
          for (int dt = 0; dt < 4; ++dt) o[mi][dt][r] *= alpha;
          mrow[mi][r] = mnew;
        }
    }
    #pragma unroll
    for (int mi = 0; mi < 2; ++mi)
      #pragma unroll
      for (int r = 0; r < 4; ++r){
        int row = mi * 16 + g * 4 + r;
        float mb = mrow[mi][r] * 1.44269504f;
        float pp[4];
        #pragma unroll
        for (int ni = 0; ni < 4; ++ni){
          pp[ni] = exp2f(__builtin_fmaf(S[mi][ni][r], 1.44269504f, -mb));
          *(ushort*)(Pw + row * 128 + (((ni * 32 + 2 * c) ^ ((row & 7) << 4)))) = f2bf(pp[ni]);
        }
        lpart[mi][r] += (pp[0] + pp[1]) + (pp[2] + pp[3]);
      }
    __builtin_amdgcn_sched_barrier(0);   // wave-private P: writes before reads

    bf16x8 vf[4][2];
    #pragma unroll
    for (int dt = 0; dt < 4; ++dt)
      #pragma unroll
      for (int ks = 0; ks < 2; ++ks)
        vf[dt][ks] = *(const bf16x8*)(Vbuf + (dt * 16 + c) * 128 + (((ks * 4 + g) ^ (c & 7)) << 4));
    #pragma unroll
    for (int mi = 0; mi < 2; ++mi){
      #pragma unroll
      for (int ks = 0; ks < 2; ++ks){
        bf16x8 pf = *(const bf16x8*)(Pw + (mi * 16 + c) * 128 + ((((ks * 4 + g) ^ (c & 7)) << 4)));
        #pragma unroll
        for (int dt = 0; dt < 4; ++dt)
          o[mi][dt] = __builtin_amdgcn_mfma_f32_16x16x32_bf16(pf, vf[dt][ks], o[mi][dt], 0, 0, 0);
      }
    }
    __builtin_amdgcn_sched_barrier(0);
  };

  int nchA = 2 * qbA + 2;                     // total staged chunks (>= 18)

  stageKV(0, 0);
  stageKV(1, 64);
  asm volatile("s_waitcnt vmcnt(4)" ::: "memory");   // buf0 ready (qf also drained)
  __builtin_amdgcn_sched_barrier(0);
  __builtin_amdgcn_s_barrier();

  int bufC = 0;                               // ch % 3
  for (int ch = 0; ch < nchA; ++ch){
    int s0 = ch * 64;
    bool staged = (ch + 2 < nchA);
    if (staged) stageKV((bufC == 0) ? 2 : bufC - 1, s0 + 128);   // (ch+2)%3

    const char* Kbuf = (const char*)&Ksm[bufC][0];
    const char* Vbuf = (const char*)&Vsm[bufC][0];
    if (s0 <= q0A + 31)
      computeTile(qfA, oA, mA, lA, q0A, s0, Kbuf, Vbuf);
    if (s0 <= q0B + 31)
      computeTile(qfB, oB, mB, lB, q0B, s0, Kbuf, Vbuf);

    if (staged) asm volatile("s_waitcnt vmcnt(4)" ::: "memory");
    else        asm volatile("s_waitcnt vmcnt(0)" ::: "memory");
    __builtin_amdgcn_sched_barrier(0);
    __builtin_amdgcn_s_barrier();
    bufC = (bufC == 2) ? 0 : bufC + 1;
  }

  // final denominator reduce + writes, both tiles
  int b = bh >> 4, h = bh & 15;
  #pragma unroll
  for (int mi = 0; mi < 2; ++mi)
    #pragma unroll
    for (int r = 0; r < 4; ++r){
      float la = lA[mi][r];
      la += __shfl_xor(la, 1); la += __shfl_xor(la, 2);
      la += __shfl_xor(la, 4); la += __shfl_xor(la, 8);
      float lia = 1.0f / la;
      float lb = lB[mi][r];
      lb += __shfl_xor(lb, 1); lb += __shfl_xor(lb, 2);
      lb += __shfl_xor(lb, 4); lb += __shfl_xor(lb, 8);
      float lib = 1.0f / lb;
      #pragma unroll
      for (int dt = 0; dt < 4; ++dt){
        int tA = q0A + mi * 16 + g * 4 + r;
        int tB = q0B + mi * 16 + g * 4 + r;
        attnb[((size_t)(b * Tt + tA)) * Cc + h * HSs + dt * 16 + c] = f2bf(oA[mi][dt][r] * lia);
        attnb[((size_t)(b * Tt + tB)) * Cc + h * HSs + dt * 16 + c] = f2bf(oB[mi][dt][r] * lib);
      }
    }
}

extern "C" void kernel_launch(void* const* d_in, const int* in_sizes, int n_in,
                              void* d_out, int out_size, void* d_ws, size_t ws_size,
                              hipStream_t stream) {
  (void)in_sizes; (void)n_in; (void)out_size; (void)ws_size;
  const float* x    = (const float*)d_in[0];
  const float* wq   = (const float*)d_in[2];
  const float* wk   = (const float*)d_in[3];
  const float* wv   = (const float*)d_in[4];
  const float* ln1g = (const float*)d_in[5];
  const float* ln1b = (const float*)d_in[6];
  const float* ln2g = (const float*)d_in[7];
  const float* ln2b = (const float*)d_in[8];
  const float* w1   = (const float*)d_in[9];
  const float* b1   = (const float*)d_in[10];
  const float* w2   = (const float*)d_in[11];
  const float* b2   = (const float*)d_in[12];
  float* out = (float*)d_out;

  char* ws = (char*)d_ws;
  const size_t SZ_ACT = (size_t)Bb * Tt * Cc * 2;
  ushort* h1    = (ushort*)(ws);
  ushort* qbuf  = (ushort*)(ws + SZ_ACT);
  ushort* kbuf  = (ushort*)(ws + 2 * SZ_ACT);
  ushort* vbuf  = (ushort*)(ws + 3 * SZ_ACT);   // V^T [B,H,HS,T]
  ushort* attnb = (ushort*)(ws + 4 * SZ_ACT);
  ushort* h2    = (ushort*)(ws + 5 * SZ_ACT);
  ushort* h3    = (ushort*)(ws + 6 * SZ_ACT);
  char*   wsw   = ws + 6 * SZ_ACT + (size_t)Bb * Tt * 4 * Cc * 2;
  ushort* wqb = (ushort*)(wsw);                 // wq,wk,wv contiguous -> [3072,1024]
  ushort* wkb = (ushort*)(wsw + (size_t)Cc * Cc * 2);
  ushort* wvb = (ushort*)(wsw + 2 * (size_t)Cc * Cc * 2);
  ushort* w1b = (ushort*)(wsw + 3 * (size_t)Cc * Cc * 2);
  ushort* w2b = (ushort*)(wsw + 3 * (size_t)Cc * Cc * 2 + (size_t)4 * Cc * Cc * 2);

  cast_bf16_kernel<<<dim3(Cc * Cc / 1024), 256, 0, stream>>>(wq, wqb);
  cast_bf16_kernel<<<dim3(Cc * Cc / 1024), 256, 0, stream>>>(wk, wkb);
  cast_bf16_kernel<<<dim3(Cc * Cc / 1024), 256, 0, stream>>>(wv, wvb);
  cast_bf16_kernel<<<dim3(4 * Cc * Cc / 1024), 256, 0, stream>>>(w1, w1b);
  cast_bf16_kernel<<<dim3(4 * Cc * Cc / 1024), 256, 0, stream>>>(w2, w2b);

  ln1_kernel<<<dim3(Bb * Tt), 256, 0, stream>>>(x, ln1g, ln1b, h1);

  // fused QKV projection: [8192,3072] = h1 @ [3072,1024]^T, 256^2 8-phase
  gemm256_kernel<0><<<dim3(32 * 12), 512, 0, stream>>>(h1, wqb, 3 * Cc, Cc, qbuf, nullptr, nullptr);

  attn_kernel<<<dim3(8, Bb * Hh), 256, 0, stream>>>(qbuf, kbuf, vbuf, attnb);

  ln2_kernel<<<dim3(Bb * Tt), 256, 0, stream>>>(x, attnb, ln2g, ln2b, out, h2);

  // FFN1: [8192,4096] = h2 @ w1^T, 256^2 8-phase, SiLU epilogue
  gemm256_kernel<1><<<dim3(32 * 16), 512, 0, stream>>>(h2, w1b, 4 * Cc, Cc, h3, nullptr, b1);
  // FFN2: 128^2 kernel, residual epilogue
  gemm_bt2_kernel<<<dim3(8, 64), 256, 0, stream>>>(h3, w2b, Cc, 4 * Cc, out, b2);
}